// Round 1
// baseline (3227.175 us; speedup 1.0000x reference)
//
#include <hip/hip_runtime.h>

// SRU++ forward, MI355X. Round 1: correctness-first all-f32 baseline.
// Shapes: B=4, L=2048, d=1024, p=256, H=4, hd=64, nl=2.
#define L_SEQ  2048
#define BATCH  4
#define DMODEL 1024
#define PDIM   256
#define NHEADS 4
#define HDIM   64
#define NLAYERS 2
#define CHUNK  256
#define NCHUNK (L_SEQ / CHUNK)

static __device__ __forceinline__ float sigmoidf_(float x) {
    return 1.0f / (1.0f + __expf(-x));
}

// ---------------------------------------------------------------------------
// Generic f32 GEMM: C = A(MxK) @ B(KxN), row-major, all dims % 64 (N), %16 (K).
// 64x64 tile, BK=16, 256 threads, 4x4 micro-tile per thread.
// blockIdx.z batches A/C by aStrideZ/cStrideZ (used for chunked U GEMM).
// ---------------------------------------------------------------------------
__global__ __launch_bounds__(256) void gemm64(
    const float* __restrict__ A, const float* __restrict__ B, float* __restrict__ C,
    int N, int K, int lda, int ldb, int ldc, long aStrideZ, long cStrideZ)
{
    A += (long)blockIdx.z * aStrideZ;
    C += (long)blockIdx.z * cStrideZ;
    __shared__ float As[16][64];   // As[k][m] (A tile transposed)
    __shared__ float Bs[16][64];   // Bs[k][n]
    const int tid = threadIdx.x;
    const int tx = tid & 15, ty = tid >> 4;
    const long row0 = (long)blockIdx.y * 64;
    const int  col0 = blockIdx.x * 64;
    const int am = tid >> 2, ak = (tid & 3) * 4;   // A loader: row am, k-offset ak
    const int bk = tid >> 4, bn = (tid & 15) * 4;  // B loader: k-row bk, col bn
    float acc[4][4] = {};
    for (int k0 = 0; k0 < K; k0 += 16) {
        float4 av = *(const float4*)&A[(row0 + am) * lda + k0 + ak];
        float4 bv = *(const float4*)&B[(long)(k0 + bk) * ldb + col0 + bn];
        __syncthreads();   // previous tile's compute done before overwrite
        As[ak + 0][am] = av.x; As[ak + 1][am] = av.y;
        As[ak + 2][am] = av.z; As[ak + 3][am] = av.w;
        *(float4*)&Bs[bk][bn] = bv;
        __syncthreads();
        #pragma unroll
        for (int k = 0; k < 16; k++) {
            float4 a4 = *(const float4*)&As[k][ty * 4];
            float4 b4 = *(const float4*)&Bs[k][tx * 4];
            float ar[4] = {a4.x, a4.y, a4.z, a4.w};
            float br[4] = {b4.x, b4.y, b4.z, b4.w};
            #pragma unroll
            for (int ii = 0; ii < 4; ii++)
                #pragma unroll
                for (int jj = 0; jj < 4; jj++)
                    acc[ii][jj] += ar[ii] * br[jj];
        }
    }
    #pragma unroll
    for (int ii = 0; ii < 4; ii++) {
        float4 cv = make_float4(acc[ii][0], acc[ii][1], acc[ii][2], acc[ii][3]);
        *(float4*)&C[(row0 + ty * 4 + ii) * ldc + col0 + tx * 4] = cv;
    }
}

// ---------------------------------------------------------------------------
// LayerNorm over last dim (p=256), one block per row.
// ---------------------------------------------------------------------------
__global__ __launch_bounds__(256) void ln_kernel(
    const float* __restrict__ z, const float* __restrict__ g,
    const float* __restrict__ b, float* __restrict__ zn)
{
    const long row = blockIdx.x;
    const int tid = threadIdx.x;
    float v = z[row * PDIM + tid];
    float s = v, sq = v * v;
    #pragma unroll
    for (int o = 32; o > 0; o >>= 1) {
        s  += __shfl_down(s, o, 64);
        sq += __shfl_down(sq, o, 64);
    }
    __shared__ float ss[4], sqs[4];
    if ((tid & 63) == 0) { ss[tid >> 6] = s; sqs[tid >> 6] = sq; }
    __syncthreads();
    s  = ss[0] + ss[1] + ss[2] + ss[3];
    sq = sqs[0] + sqs[1] + sqs[2] + sqs[3];
    const float mean = s * (1.0f / PDIM);
    const float var  = sq * (1.0f / PDIM) - mean * mean;
    const float rstd = rsqrtf(var + 1e-5f);
    zn[row * PDIM + tid] = (v - mean) * rstd * g[tid] + b[tid];
}

// ---------------------------------------------------------------------------
// Flash attention (f32, online softmax) fused with  t = ao*alpha + residual.
// Grid: (L/64 q-tiles, B*H). Block 256 = 4 waves.
// Thread (i = tid&63, grp = tid>>6): owns S row i, O dims [grp*16, grp*16+16).
// In-place: tout == zn is safe (each block writes only the q-rows/cols it read
// into registers at kernel start; regions are disjoint across blocks).
// ---------------------------------------------------------------------------
__global__ __launch_bounds__(256) void attn64(
    const float* __restrict__ zn, const float* __restrict__ kv,
    const float* __restrict__ zres, const float* __restrict__ alpha_p,
    float* __restrict__ tout)
{
    const int b   = blockIdx.y >> 2;
    const int h   = blockIdx.y & 3;
    const int q0  = blockIdx.x * 64;
    const int tid = threadIdx.x;
    const int i   = tid & 63;
    const int grp = tid >> 6;

    __shared__ float Ks[64][68];   // pad 68: conflict-free strided reads, 16B-aligned
    __shared__ float Vs[64][68];
    __shared__ float Ss[64][65];
    __shared__ float mrow[64], lrow[64], rs_s[64];

    // q row (scaled) into registers: 64 VGPRs
    float q[64];
    const long qbase = ((long)b * L_SEQ + q0 + i) * PDIM + h * HDIM;
    #pragma unroll
    for (int d = 0; d < 64; d += 4) {
        float4 v4 = *(const float4*)&zn[qbase + d];
        q[d]   = v4.x * 0.125f; q[d+1] = v4.y * 0.125f;
        q[d+2] = v4.z * 0.125f; q[d+3] = v4.w * 0.125f;
    }
    float O[16] = {};
    if (tid < 64) { mrow[tid] = -3.0e38f; lrow[tid] = 0.0f; }
    __syncthreads();

    const long kvb = (long)b * L_SEQ * (2 * PDIM) + h * HDIM;
    for (int kt = 0; kt < L_SEQ / 64; kt++) {
        // stage K,V tile (64 keys x 64 dims)
        for (int e = tid; e < 64 * 16; e += 256) {
            int j = e >> 4, d4 = (e & 15) * 4;
            long base = kvb + (long)(kt * 64 + j) * (2 * PDIM);
            *(float4*)&Ks[j][d4] = *(const float4*)&kv[base + d4];
            *(float4*)&Vs[j][d4] = *(const float4*)&kv[base + PDIM + d4];
        }
        __syncthreads();
        // S[i][j] = q_i . k_j
        #pragma unroll 2
        for (int jj = 0; jj < 16; jj++) {
            int j = grp * 16 + jj;
            float acc = 0.0f;
            #pragma unroll
            for (int d = 0; d < 64; d += 4) {
                float4 kf = *(const float4*)&Ks[j][d];
                acc += q[d] * kf.x + q[d+1] * kf.y + q[d+2] * kf.z + q[d+3] * kf.w;
            }
            Ss[i][j] = acc;
        }
        __syncthreads();
        // online softmax bookkeeping (wave 0 only)
        if (tid < 64) {
            float mo = mrow[tid];
            float mx = mo;
            for (int j = 0; j < 64; j++) mx = fmaxf(mx, Ss[tid][j]);
            float rs = __expf(mo - mx);
            float s = 0.0f;
            for (int j = 0; j < 64; j++) {
                float p = __expf(Ss[tid][j] - mx);
                Ss[tid][j] = p;
                s += p;
            }
            mrow[tid] = mx;
            lrow[tid] = lrow[tid] * rs + s;
            rs_s[tid] = rs;
        }
        __syncthreads();
        // O = O*rs + P @ V
        float rs = rs_s[i];
        #pragma unroll
        for (int d = 0; d < 16; d++) O[d] *= rs;
        #pragma unroll 4
        for (int j = 0; j < 64; j++) {
            float p = Ss[i][j];
            const float4* vr = (const float4*)&Vs[j][grp * 16];
            #pragma unroll
            for (int d4 = 0; d4 < 4; d4++) {
                float4 vv = vr[d4];
                O[d4*4+0] += p * vv.x; O[d4*4+1] += p * vv.y;
                O[d4*4+2] += p * vv.z; O[d4*4+3] += p * vv.w;
            }
        }
        __syncthreads();
    }
    const float linv = 1.0f / lrow[i];
    const float a = alpha_p[0];
    const long obase = ((long)b * L_SEQ + q0 + i) * PDIM + h * HDIM + grp * 16;
    #pragma unroll
    for (int d = 0; d < 16; d++)
        tout[obase + d] = O[d] * linv * a + zres[obase + d];
}

// ---------------------------------------------------------------------------
// SRU recurrence, one CHUNK of timesteps. 4096 threads = (b, ch) channels.
// cstate lives in d_out's c_finals region; chunk 0 seeds from c0 so every
// kernel_launch call is deterministic.  Layer-1 in-place h is safe: x is read
// at (b,t,ch) before h is written there, by the same thread.
// ---------------------------------------------------------------------------
__global__ __launch_bounds__(256) void scan_chunk(
    const float* __restrict__ Uc,     // (B, CHUNK, 3*DMODEL)
    const float* __restrict__ xin,    // (B, L, D)
    float* __restrict__ hout,         // (B, L, D)
    float* __restrict__ cstate,       // (B*D)
    const float* __restrict__ c0,     // (B*D)
    const float* __restrict__ wcl,    // (2*D)
    const float* __restrict__ biasl,  // (2*D)
    int chunk)
{
    const int gid = blockIdx.x * 256 + threadIdx.x;  // 0..4095
    const int b = gid >> 10, ch = gid & 1023;
    const float vf = wcl[ch],        vr = wcl[DMODEL + ch];
    const float bf = biasl[ch],      br = biasl[DMODEL + ch];
    float c = (chunk == 0) ? c0[gid] : cstate[gid];
    const float* u = Uc + (long)b * CHUNK * (3 * DMODEL) + ch;
    const long xoff = (long)b * L_SEQ * DMODEL + (long)chunk * CHUNK * DMODEL + ch;
    const float* x = xin + xoff;
    float* hp = hout + xoff;
    for (int t = 0; t < CHUNK; t++) {
        float u0 = u[(long)t * 3072];
        float u1 = u[(long)t * 3072 + 1024];
        float u2 = u[(long)t * 3072 + 2048];
        float xv = x[(long)t * 1024];
        float f = sigmoidf_(u1 + bf + vf * c);
        c = u0 + (c - u0) * f;
        float r = sigmoidf_(u2 + br + vr * c);
        hp[(long)t * 1024] = (c - xv) * r + xv;
    }
    cstate[gid] = c;
}

// ---------------------------------------------------------------------------
extern "C" void kernel_launch(void* const* d_in, const int* in_sizes, int n_in,
                              void* d_out, int out_size, void* d_ws, size_t ws_size,
                              hipStream_t stream)
{
    const float* x     = (const float*)d_in[0];
    const float* W1    = (const float*)d_in[1];
    const float* ln_g  = (const float*)d_in[2];
    const float* ln_b  = (const float*)d_in[3];
    const float* W2    = (const float*)d_in[4];
    const float* alpha = (const float*)d_in[5];
    const float* W3    = (const float*)d_in[6];
    const float* wc    = (const float*)d_in[7];
    const float* bias  = (const float*)d_in[8];
    const float* c0    = (const float*)d_in[9];

    float* hout = (float*)d_out;                              // (B,L,D)
    float* cout = hout + (long)BATCH * L_SEQ * DMODEL;        // (nl,B,D)

    // workspace: z 8.4MB | kv 16.8MB | zn/ao/t 8.4MB | U-chunk 12.6MB  (~46MB)
    float* z  = (float*)d_ws;
    float* kv = z  + (long)BATCH * L_SEQ * PDIM;
    float* zn = kv + (long)BATCH * L_SEQ * 2 * PDIM;
    float* Uc = zn + (long)BATCH * L_SEQ * PDIM;

    const int MROWS = BATCH * L_SEQ;  // 8192

    for (int l = 0; l < NLAYERS; l++) {
        const float* hin = (l == 0) ? x : hout;

        // z = hin @ W1[l]          (8192 x 1024 x 256)
        gemm64<<<dim3(PDIM / 64, MROWS / 64, 1), 256, 0, stream>>>(
            hin, W1 + (long)l * DMODEL * PDIM, z,
            PDIM, DMODEL, DMODEL, PDIM, PDIM, 0, 0);

        // zn = LayerNorm(z)
        ln_kernel<<<MROWS, 256, 0, stream>>>(z, ln_g + l * PDIM, ln_b + l * PDIM, zn);

        // kv = zn @ W2[l]          (8192 x 256 x 512)
        gemm64<<<dim3(2 * PDIM / 64, MROWS / 64, 1), 256, 0, stream>>>(
            zn, W2 + (long)l * PDIM * 2 * PDIM, kv,
            2 * PDIM, PDIM, PDIM, 2 * PDIM, 2 * PDIM, 0, 0);

        // t = attn(zn; kv)*alpha + z   (written in-place into zn)
        attn64<<<dim3(L_SEQ / 64, BATCH * NHEADS), 256, 0, stream>>>(
            zn, kv, z, alpha + l, zn);

        // U = t @ W3[l] in CHUNK-of-timesteps slabs, then the recurrence
        for (int cch = 0; cch < NCHUNK; cch++) {
            gemm64<<<dim3(3 * DMODEL / 64, CHUNK / 64, BATCH), 256, 0, stream>>>(
                zn + (long)cch * CHUNK * PDIM, W3 + (long)l * PDIM * 3 * DMODEL, Uc,
                3 * DMODEL, PDIM, PDIM, 3 * DMODEL, 3 * DMODEL,
                (long)L_SEQ * PDIM, (long)CHUNK * 3 * DMODEL);
            scan_chunk<<<16, 256, 0, stream>>>(
                Uc, hin, hout,
                cout + (long)l * BATCH * DMODEL, c0 + (long)l * BATCH * DMODEL,
                wc + (long)l * 2 * DMODEL, bias + (long)l * 2 * DMODEL, cch);
        }
    }
}

// Round 2
// 1516.739 us; speedup vs baseline: 2.1277x; 2.1277x over previous
//
#include <hip/hip_runtime.h>
#include <hip/hip_bf16.h>

// SRU++ forward, MI355X. Round 2: bf16 MFMA GEMMs + MFMA flash attention.
// Shapes: B=4, L=2048, d=1024, p=256, H=4, hd=64, nl=2.
#define L_SEQ  2048
#define BATCH  4
#define DMODEL 1024
#define PDIM   256
#define NHEADS 4
#define HDIM   64
#define NLAYERS 2
#define CHUNK  256
#define NCHUNK (L_SEQ / CHUNK)

typedef __attribute__((ext_vector_type(8))) short sv8;   // 8 bf16 (4 VGPRs) MFMA A/B frag
typedef __attribute__((ext_vector_type(4))) short sv4;
typedef __attribute__((ext_vector_type(4))) float fv4;   // MFMA C/D frag

static __device__ __forceinline__ short f2bs(float f) {
    union { __hip_bfloat16 h; short s; } u;
    u.h = __float2bfloat16(f);
    return u.s;
}
static __device__ __forceinline__ float sigmoidf_(float x) {
    return 1.0f / (1.0f + __expf(-x));
}

// ---------------------------------------------------------------------------
// bf16 MFMA GEMM: C = A(MxK,bf16,row-major) @ Bt^T (Bt = [N][K] bf16 row-major).
// BM=128, BK=64, 256 threads = 4 waves (2x2), wave tile 64 x BN/2.
// LDS 16B-slot XOR swizzle (slot ^= row&7) -> conflict-free frag reads.
// A/B frag mapping (16x16x32): lane l holds row/col = l&15, k = (l>>4)*8+j (+32*kk).
// C/D: col = l&15, row = (l>>4)*4 + reg   [verified layout, learn_hip m89/m91].
// ---------------------------------------------------------------------------
template<int BN, bool OUT_BF16>
__global__ __launch_bounds__(256) void gemm_mfma(
    const ushort* __restrict__ A, const ushort* __restrict__ Bt,
    void* __restrict__ Cout, int N, int K, long aStrideZ, long cStrideZ)
{
    constexpr int BM = 128;
    constexpr int WN = BN / 2, NI = WN / 16;
    const ushort* Ag = A + (long)blockIdx.z * aStrideZ;
    const long row0 = (long)blockIdx.y * BM;
    const int col0 = blockIdx.x * BN;
    __shared__ ushort As[BM * 64];
    __shared__ ushort Bs[BN * 64];
    const int tid = threadIdx.x;
    const int l = tid & 63, w = tid >> 6;
    const int lg = l >> 4, lr = l & 15;
    const int wr = w >> 1, wc = w & 1;

    fv4 acc[4][NI];
    #pragma unroll
    for (int mi = 0; mi < 4; mi++)
        #pragma unroll
        for (int ni = 0; ni < NI; ni++)
            acc[mi][ni] = (fv4){0.f, 0.f, 0.f, 0.f};

    for (int k0 = 0; k0 < K; k0 += 64) {
        __syncthreads();
        #pragma unroll
        for (int i = 0; i < 4; i++) {            // A tile: 128x64 bf16 = 1024 slots
            int s = tid + i * 256;
            int r = s >> 3, sl = s & 7;
            sv8 v = *(const sv8*)&Ag[(row0 + r) * K + k0 + sl * 8];
            *(sv8*)&As[r * 64 + ((sl ^ (r & 7)) * 8)] = v;
        }
        #pragma unroll
        for (int i = 0; i < BN / 32; i++) {      // B tile: BNx64
            int s = tid + i * 256;
            int r = s >> 3, sl = s & 7;
            sv8 v = *(const sv8*)&Bt[(long)(col0 + r) * K + k0 + sl * 8];
            *(sv8*)&Bs[r * 64 + ((sl ^ (r & 7)) * 8)] = v;
        }
        __syncthreads();
        #pragma unroll
        for (int kk = 0; kk < 2; kk++) {
            sv8 af[4], bfr[NI];
            #pragma unroll
            for (int mi = 0; mi < 4; mi++) {
                int r = wr * 64 + mi * 16 + lr;
                af[mi] = *(const sv8*)&As[r * 64 + (((kk * 4 + lg) ^ (r & 7)) * 8)];
            }
            #pragma unroll
            for (int ni = 0; ni < NI; ni++) {
                int r = wc * WN + ni * 16 + lr;
                bfr[ni] = *(const sv8*)&Bs[r * 64 + (((kk * 4 + lg) ^ (r & 7)) * 8)];
            }
            #pragma unroll
            for (int mi = 0; mi < 4; mi++)
                #pragma unroll
                for (int ni = 0; ni < NI; ni++)
                    acc[mi][ni] = __builtin_amdgcn_mfma_f32_16x16x32_bf16(
                        af[mi], bfr[ni], acc[mi][ni], 0, 0, 0);
        }
    }
    #pragma unroll
    for (int mi = 0; mi < 4; mi++)
        #pragma unroll
        for (int ni = 0; ni < NI; ni++)
            #pragma unroll
            for (int e = 0; e < 4; e++) {
                long row = row0 + wr * 64 + mi * 16 + lg * 4 + e;
                int col = col0 + wc * WN + ni * 16 + lr;
                long idx = (long)blockIdx.z * cStrideZ + row * N + col;
                if (OUT_BF16) ((ushort*)Cout)[idx] = f2bs(acc[mi][ni][e]);
                else          ((float*)Cout)[idx]  = acc[mi][ni][e];
            }
}

// ---------------------------------------------------------------------------
// LayerNorm over p=256, one block/row; f32 in, bf16 out.
// ---------------------------------------------------------------------------
__global__ __launch_bounds__(256) void ln_kernel(
    const float* __restrict__ z, const float* __restrict__ g,
    const float* __restrict__ b, ushort* __restrict__ znb)
{
    const long row = blockIdx.x;
    const int tid = threadIdx.x;
    float v = z[row * PDIM + tid];
    float s = v, sq = v * v;
    #pragma unroll
    for (int o = 32; o > 0; o >>= 1) {
        s  += __shfl_down(s, o, 64);
        sq += __shfl_down(sq, o, 64);
    }
    __shared__ float ss[4], sqs[4];
    if ((tid & 63) == 0) { ss[tid >> 6] = s; sqs[tid >> 6] = sq; }
    __syncthreads();
    s  = ss[0] + ss[1] + ss[2] + ss[3];
    sq = sqs[0] + sqs[1] + sqs[2] + sqs[3];
    const float mean = s * (1.0f / PDIM);
    const float var  = sq * (1.0f / PDIM) - mean * mean;
    const float rstd = rsqrtf(var + 1e-5f);
    znb[row * PDIM + tid] = f2bs((v - mean) * rstd * g[tid] + b[tid]);
}

// ---------------------------------------------------------------------------
// MFMA flash attention + epilogue t = ao*alpha + z  (bf16 out).
// Grid (L/64, B*H), 256 thr = 4 waves; wave owns 16 q-rows.
// Swapped QK^T: S^T[key][q] = K·Q^T so softmax reduce = 4x4 regs + shfl_xor(16,32).
// P round-trips through per-wave LDS (swizzled) into A-frag layout for PV.
// V staged transposed [dim][key] with 72-elem padded rows (aligned b128 reads).
// ---------------------------------------------------------------------------
__global__ __launch_bounds__(256) void attn_mfma(
    const ushort* __restrict__ znb, const ushort* __restrict__ kvb,
    const float* __restrict__ zres, const float* __restrict__ alpha_p,
    ushort* __restrict__ tb)
{
    const int b = blockIdx.y >> 2, h = blockIdx.y & 3;
    const int q0 = blockIdx.x * 64;
    const int tid = threadIdx.x;
    const int l = tid & 63, w = tid >> 6;
    const int lg = l >> 4, lr = l & 15;

    __shared__ ushort Ks[64 * 64];      // [key][dim], 16B-slot swizzled
    __shared__ ushort Vt[64 * 72];      // [dim][key], padded stride 72
    __shared__ ushort Pt[4][16 * 64];   // per-wave P[q][key], swizzled

    const long qrow = (long)b * L_SEQ + q0 + w * 16 + lr;
    const sv8 qf0 = *(const sv8*)&znb[qrow * PDIM + h * 64 + lg * 8];
    const sv8 qf1 = *(const sv8*)&znb[qrow * PDIM + h * 64 + 32 + lg * 8];

    float m_col = -3.0e38f, l_col = 0.0f;
    fv4 o_acc[4];
    #pragma unroll
    for (int nt = 0; nt < 4; nt++) o_acc[nt] = (fv4){0.f, 0.f, 0.f, 0.f};

    const ushort* kvh = kvb + (long)b * L_SEQ * 512 + h * 64;

    for (int kt = 0; kt < L_SEQ / 64; kt++) {
        __syncthreads();
        #pragma unroll
        for (int i = 0; i < 2; i++) {            // K straight, swizzled
            int s = tid + i * 256;
            int r = s >> 3, sl = s & 7;
            sv8 v = *(const sv8*)&kvh[(long)(kt * 64 + r) * 512 + sl * 8];
            *(sv8*)&Ks[r * 64 + ((sl ^ (r & 7)) * 8)] = v;
        }
        #pragma unroll
        for (int i = 0; i < 2; i++) {            // V transposed (rotated scatter)
            int s = tid + i * 256;
            int key = s >> 3, dblk = s & 7;
            sv8 v = *(const sv8*)&kvh[(long)(kt * 64 + key) * 512 + 256 + dblk * 8];
            #pragma unroll
            for (int j = 0; j < 8; j++) {
                int jj = (j + dblk) & 7;         // vary dim&7 across lanes per inst
                Vt[(dblk * 8 + jj) * 72 + key] = ((const ushort*)&v)[jj];
            }
        }
        __syncthreads();

        // S^T = K · Q^T   (4 key-tiles x K=64)
        fv4 st[4];
        #pragma unroll
        for (int mt = 0; mt < 4; mt++) {
            st[mt] = (fv4){0.f, 0.f, 0.f, 0.f};
            int r = mt * 16 + lr;
            sv8 ka0 = *(const sv8*)&Ks[r * 64 + ((lg ^ (r & 7)) * 8)];
            sv8 ka1 = *(const sv8*)&Ks[r * 64 + (((4 + lg) ^ (r & 7)) * 8)];
            st[mt] = __builtin_amdgcn_mfma_f32_16x16x32_bf16(ka0, qf0, st[mt], 0, 0, 0);
            st[mt] = __builtin_amdgcn_mfma_f32_16x16x32_bf16(ka1, qf1, st[mt], 0, 0, 0);
        }
        // online softmax (per q-col = lr; keys live in 4 regs x 4 mt + lane groups)
        float mx = m_col;
        #pragma unroll
        for (int mt = 0; mt < 4; mt++)
            #pragma unroll
            for (int e = 0; e < 4; e++)
                mx = fmaxf(mx, st[mt][e] * 0.125f);
        mx = fmaxf(mx, __shfl_xor(mx, 16));
        mx = fmaxf(mx, __shfl_xor(mx, 32));
        float ps = 0.f;
        #pragma unroll
        for (int mt = 0; mt < 4; mt++)
            #pragma unroll
            for (int e = 0; e < 4; e++) {
                float p = __expf(st[mt][e] * 0.125f - mx);
                st[mt][e] = p;
                ps += p;
            }
        float rs = __expf(m_col - mx);
        ps += __shfl_xor(ps, 16);
        ps += __shfl_xor(ps, 32);
        l_col = l_col * rs + ps;
        m_col = mx;
        // P -> per-wave LDS (bf16) in A-frag-friendly [q][key] layout
        #pragma unroll
        for (int mt = 0; mt < 4; mt++) {
            sv4 pw;
            pw[0] = f2bs(st[mt][0]); pw[1] = f2bs(st[mt][1]);
            pw[2] = f2bs(st[mt][2]); pw[3] = f2bs(st[mt][3]);
            int slot = 2 * mt + (lg >> 1);
            int idx = lr * 64 + ((slot ^ (lr & 7)) * 8) + 4 * (lg & 1);
            *(sv4*)&Pt[w][idx] = pw;
        }
        // O rescale (rows are q: fetch rs for q = lg*4+e from lane q)
        float rs_row[4];
        #pragma unroll
        for (int e = 0; e < 4; e++) rs_row[e] = __shfl(rs, lg * 4 + e);
        #pragma unroll
        for (int nt = 0; nt < 4; nt++)
            #pragma unroll
            for (int e = 0; e < 4; e++)
                o_acc[nt][e] *= rs_row[e];
        // O += P @ V
        #pragma unroll
        for (int kk = 0; kk < 2; kk++) {
            sv8 pa = *(const sv8*)&Pt[w][lr * 64 + (((kk * 4 + lg) ^ (lr & 7)) * 8)];
            #pragma unroll
            for (int nt = 0; nt < 4; nt++) {
                int dim = nt * 16 + lr;
                sv8 vb = *(const sv8*)&Vt[dim * 72 + kk * 32 + lg * 8];
                o_acc[nt] = __builtin_amdgcn_mfma_f32_16x16x32_bf16(pa, vb, o_acc[nt], 0, 0, 0);
            }
        }
    }
    float linv = 1.0f / l_col;
    float li_row[4];
    #pragma unroll
    for (int e = 0; e < 4; e++) li_row[e] = __shfl(linv, lg * 4 + e);
    const float a = alpha_p[0];
    #pragma unroll
    for (int nt = 0; nt < 4; nt++)
        #pragma unroll
        for (int e = 0; e < 4; e++) {
            long row = (long)b * L_SEQ + q0 + w * 16 + lg * 4 + e;
            int col = h * 64 + nt * 16 + lr;
            float t = o_acc[nt][e] * li_row[e] * a + zres[row * PDIM + col];
            tb[row * PDIM + col] = f2bs(t);
        }
}

// ---------------------------------------------------------------------------
// f32 -> bf16 cast (x -> hb), 4 elems/thread.
// ---------------------------------------------------------------------------
__global__ __launch_bounds__(256) void cast_bf16(
    const float* __restrict__ in, ushort* __restrict__ out)
{
    long i = (long)blockIdx.x * 256 + threadIdx.x;
    float4 v = ((const float4*)in)[i];
    sv4 o;
    o[0] = f2bs(v.x); o[1] = f2bs(v.y); o[2] = f2bs(v.z); o[3] = f2bs(v.w);
    *(sv4*)&out[i * 4] = o;
}

// ---------------------------------------------------------------------------
// Weight transpose + cast: W[K][N] f32 -> Wt[N][K] bf16 (32x32 tiles).
// ---------------------------------------------------------------------------
__global__ __launch_bounds__(256) void tcast(
    const float* __restrict__ W, ushort* __restrict__ Wt, int K, int N)
{
    __shared__ float t[32][33];
    const int n0 = blockIdx.x * 32, k0 = blockIdx.y * 32;
    const int c = threadIdx.x & 31, r = threadIdx.x >> 5;
    #pragma unroll
    for (int i = 0; i < 4; i++)
        t[r + i * 8][c] = W[(long)(k0 + r + i * 8) * N + n0 + c];
    __syncthreads();
    #pragma unroll
    for (int i = 0; i < 4; i++)
        Wt[(long)(n0 + r + i * 8) * K + k0 + c] = f2bs(t[c][r + i * 8]);
}

// ---------------------------------------------------------------------------
// SRU recurrence over one CHUNK. Writes h (f32, d_out) and h (bf16, hb).
// cstate = c_finals region of d_out; chunk 0 seeds from c0 (deterministic).
// ---------------------------------------------------------------------------
__global__ __launch_bounds__(256) void scan_chunk(
    const float* __restrict__ Uc, const float* __restrict__ xin,
    float* __restrict__ hout, ushort* __restrict__ hb,
    float* __restrict__ cstate, const float* __restrict__ c0,
    const float* __restrict__ wcl, const float* __restrict__ biasl, int chunk)
{
    const int gid = blockIdx.x * 256 + threadIdx.x;   // 0..4095
    const int b = gid >> 10, ch = gid & 1023;
    const float vf = wcl[ch],   vr = wcl[DMODEL + ch];
    const float bf = biasl[ch], br = biasl[DMODEL + ch];
    float c = (chunk == 0) ? c0[gid] : cstate[gid];
    const float* u = Uc + (long)b * CHUNK * 3072 + ch;
    const long xoff = (long)b * L_SEQ * DMODEL + (long)chunk * CHUNK * DMODEL + ch;
    const float* x = xin + xoff;
    float* hp = hout + xoff;
    ushort* hbp = hb + xoff;
    for (int t = 0; t < CHUNK; t++) {
        float u0 = u[(long)t * 3072];
        float u1 = u[(long)t * 3072 + 1024];
        float u2 = u[(long)t * 3072 + 2048];
        float xv = x[(long)t * 1024];
        float f = sigmoidf_(u1 + bf + vf * c);
        c = u0 + (c - u0) * f;
        float r = sigmoidf_(u2 + br + vr * c);
        float hv = (c - xv) * r + xv;
        hp[(long)t * 1024]  = hv;
        hbp[(long)t * 1024] = f2bs(hv);
    }
    cstate[gid] = c;
}

// ---------------------------------------------------------------------------
extern "C" void kernel_launch(void* const* d_in, const int* in_sizes, int n_in,
                              void* d_out, int out_size, void* d_ws, size_t ws_size,
                              hipStream_t stream)
{
    const float* x     = (const float*)d_in[0];
    const float* W1    = (const float*)d_in[1];
    const float* ln_g  = (const float*)d_in[2];
    const float* ln_b  = (const float*)d_in[3];
    const float* W2    = (const float*)d_in[4];
    const float* alpha = (const float*)d_in[5];
    const float* W3    = (const float*)d_in[6];
    const float* wc    = (const float*)d_in[7];
    const float* bias  = (const float*)d_in[8];
    const float* c0    = (const float*)d_in[9];

    float* hout = (float*)d_out;                              // (B,L,D)
    float* cout = hout + (long)BATCH * L_SEQ * DMODEL;        // (nl,B,D)

    // ws layout (44.3 MB total; Uc overlays dead zn/kv region during scan phase)
    ushort* hb   = (ushort*)d_ws;                             // 16.8 MB  bf16 h
    float*  z    = (float*)(hb + (long)8192 * 1024);          // 8.4 MB
    ushort* znb  = (ushort*)(z + (long)8192 * 256);           // 4.2 MB
    ushort* kvb  = znb + (long)8192 * 256;                    // 8.4 MB
    ushort* tbuf = kvb + (long)8192 * 512;                    // 4.2 MB
    ushort* W1t  = tbuf + (long)8192 * 256;                   // 0.5 MB
    ushort* W2t  = W1t + 256 * 1024;                          // 0.25 MB
    ushort* W3t  = W2t + 512 * 256;                           // 1.5 MB
    float*  Uc   = (float*)znb;  // 12.58 MB, fits exactly in znb+kvb (12.6 MB)

    // x -> bf16 (8192*1024 elems, 4/thread)
    cast_bf16<<<8192, 256, 0, stream>>>(x, hb);

    for (int l = 0; l < NLAYERS; l++) {
        // weights -> transposed bf16 [N][K]
        tcast<<<dim3(PDIM / 32, DMODEL / 32), 256, 0, stream>>>(
            W1 + (long)l * DMODEL * PDIM, W1t, DMODEL, PDIM);
        tcast<<<dim3(2 * PDIM / 32, PDIM / 32), 256, 0, stream>>>(
            W2 + (long)l * PDIM * 2 * PDIM, W2t, PDIM, 2 * PDIM);
        tcast<<<dim3(3 * DMODEL / 32, PDIM / 32), 256, 0, stream>>>(
            W3 + (long)l * PDIM * 3 * DMODEL, W3t, PDIM, 3 * DMODEL);

        // z = h @ W1   (8192 x 1024 -> 256), f32 out
        gemm_mfma<64, false><<<dim3(PDIM / 64, 8192 / 128, 1), 256, 0, stream>>>(
            hb, W1t, z, PDIM, DMODEL, 0, 0);

        // zn = LN(z) -> bf16
        ln_kernel<<<8192, 256, 0, stream>>>(z, ln_g + l * PDIM, ln_b + l * PDIM, znb);

        // kv = zn @ W2  (8192 x 256 -> 512), bf16 out
        gemm_mfma<128, true><<<dim3(512 / 128, 8192 / 128, 1), 256, 0, stream>>>(
            znb, W2t, kvb, 512, PDIM, 0, 0);

        // t = attn(zn)*alpha + z -> bf16
        attn_mfma<<<dim3(L_SEQ / 64, BATCH * NHEADS), 256, 0, stream>>>(
            znb, kvb, z, alpha + l, tbuf);

        // U = t @ W3 per chunk (f32), then recurrence
        for (int cch = 0; cch < NCHUNK; cch++) {
            gemm_mfma<128, false><<<dim3(3072 / 128, CHUNK / 128, BATCH), 256, 0, stream>>>(
                tbuf + (long)cch * CHUNK * PDIM, W3t, Uc, 3072, PDIM,
                (long)L_SEQ * PDIM, (long)CHUNK * 3072);
            scan_chunk<<<16, 256, 0, stream>>>(
                Uc, (l == 0) ? x : hout, hout, hb,
                cout + (long)l * BATCH * DMODEL, c0 + (long)l * BATCH * DMODEL,
                wc + (long)l * 2 * DMODEL, bias + (long)l * 2 * DMODEL, cch);
        }
    }
}

// Round 3
// 1393.493 us; speedup vs baseline: 2.3159x; 1.0884x over previous
//
#include <hip/hip_runtime.h>
#include <hip/hip_bf16.h>

// SRU++ forward, MI355X. Round 3: bf16 U + pipelined 64-CU scan.
// Shapes: B=4, L=2048, d=1024, p=256, H=4, hd=64, nl=2.
#define L_SEQ  2048
#define BATCH  4
#define DMODEL 1024
#define PDIM   256
#define NHEADS 4
#define HDIM   64
#define NLAYERS 2
#define SCHUNK 512
#define NCHUNK (L_SEQ / SCHUNK)

typedef __attribute__((ext_vector_type(8))) short sv8;   // 8 bf16 (4 VGPRs) MFMA A/B frag
typedef __attribute__((ext_vector_type(4))) short sv4;
typedef __attribute__((ext_vector_type(4))) float fv4;   // MFMA C/D frag

static __device__ __forceinline__ short f2bs(float f) {
    union { __hip_bfloat16 h; short s; } u;
    u.h = __float2bfloat16(f);
    return u.s;
}
static __device__ __forceinline__ float bs2f(ushort s) {
    union { float f; unsigned u; } v;
    v.u = ((unsigned)s) << 16;
    return v.f;
}
static __device__ __forceinline__ float sigmoidf_(float x) {
    return 1.0f / (1.0f + __expf(-x));
}

// ---------------------------------------------------------------------------
// bf16 MFMA GEMM: C = A(MxK,bf16,row-major) @ Bt^T (Bt = [N][K] bf16 row-major).
// BM=128, BK=64, 256 threads = 4 waves (2x2), wave tile 64 x BN/2.
// LDS 16B-slot XOR swizzle (slot ^= row&7) -> conflict-free frag reads.
// C/D: col = l&15, row = (l>>4)*4 + reg   [verified layout, learn_hip m89/m91].
// ---------------------------------------------------------------------------
template<int BN, bool OUT_BF16>
__global__ __launch_bounds__(256) void gemm_mfma(
    const ushort* __restrict__ A, const ushort* __restrict__ Bt,
    void* __restrict__ Cout, int N, int K, long aStrideZ, long cStrideZ)
{
    constexpr int BM = 128;
    constexpr int WN = BN / 2, NI = WN / 16;
    const ushort* Ag = A + (long)blockIdx.z * aStrideZ;
    const long row0 = (long)blockIdx.y * BM;
    const int col0 = blockIdx.x * BN;
    __shared__ ushort As[BM * 64];
    __shared__ ushort Bs[BN * 64];
    const int tid = threadIdx.x;
    const int l = tid & 63, w = tid >> 6;
    const int lg = l >> 4, lr = l & 15;
    const int wr = w >> 1, wc = w & 1;

    fv4 acc[4][NI];
    #pragma unroll
    for (int mi = 0; mi < 4; mi++)
        #pragma unroll
        for (int ni = 0; ni < NI; ni++)
            acc[mi][ni] = (fv4){0.f, 0.f, 0.f, 0.f};

    for (int k0 = 0; k0 < K; k0 += 64) {
        __syncthreads();
        #pragma unroll
        for (int i = 0; i < 4; i++) {            // A tile: 128x64 bf16 = 1024 slots
            int s = tid + i * 256;
            int r = s >> 3, sl = s & 7;
            sv8 v = *(const sv8*)&Ag[(row0 + r) * K + k0 + sl * 8];
            *(sv8*)&As[r * 64 + ((sl ^ (r & 7)) * 8)] = v;
        }
        #pragma unroll
        for (int i = 0; i < BN / 32; i++) {      // B tile: BNx64
            int s = tid + i * 256;
            int r = s >> 3, sl = s & 7;
            sv8 v = *(const sv8*)&Bt[(long)(col0 + r) * K + k0 + sl * 8];
            *(sv8*)&Bs[r * 64 + ((sl ^ (r & 7)) * 8)] = v;
        }
        __syncthreads();
        #pragma unroll
        for (int kk = 0; kk < 2; kk++) {
            sv8 af[4], bfr[NI];
            #pragma unroll
            for (int mi = 0; mi < 4; mi++) {
                int r = wr * 64 + mi * 16 + lr;
                af[mi] = *(const sv8*)&As[r * 64 + (((kk * 4 + lg) ^ (r & 7)) * 8)];
            }
            #pragma unroll
            for (int ni = 0; ni < NI; ni++) {
                int r = wc * WN + ni * 16 + lr;
                bfr[ni] = *(const sv8*)&Bs[r * 64 + (((kk * 4 + lg) ^ (r & 7)) * 8)];
            }
            __builtin_amdgcn_s_setprio(1);
            #pragma unroll
            for (int mi = 0; mi < 4; mi++)
                #pragma unroll
                for (int ni = 0; ni < NI; ni++)
                    acc[mi][ni] = __builtin_amdgcn_mfma_f32_16x16x32_bf16(
                        af[mi], bfr[ni], acc[mi][ni], 0, 0, 0);
            __builtin_amdgcn_s_setprio(0);
        }
    }
    #pragma unroll
    for (int mi = 0; mi < 4; mi++)
        #pragma unroll
        for (int ni = 0; ni < NI; ni++)
            #pragma unroll
            for (int e = 0; e < 4; e++) {
                long row = row0 + wr * 64 + mi * 16 + lg * 4 + e;
                int col = col0 + wc * WN + ni * 16 + lr;
                long idx = (long)blockIdx.z * cStrideZ + row * N + col;
                if (OUT_BF16) ((ushort*)Cout)[idx] = f2bs(acc[mi][ni][e]);
                else          ((float*)Cout)[idx]  = acc[mi][ni][e];
            }
}

// ---------------------------------------------------------------------------
// LayerNorm over p=256, one block/row; f32 in, bf16 out.
// ---------------------------------------------------------------------------
__global__ __launch_bounds__(256) void ln_kernel(
    const float* __restrict__ z, const float* __restrict__ g,
    const float* __restrict__ b, ushort* __restrict__ znb)
{
    const long row = blockIdx.x;
    const int tid = threadIdx.x;
    float v = z[row * PDIM + tid];
    float s = v, sq = v * v;
    #pragma unroll
    for (int o = 32; o > 0; o >>= 1) {
        s  += __shfl_down(s, o, 64);
        sq += __shfl_down(sq, o, 64);
    }
    __shared__ float ss[4], sqs[4];
    if ((tid & 63) == 0) { ss[tid >> 6] = s; sqs[tid >> 6] = sq; }
    __syncthreads();
    s  = ss[0] + ss[1] + ss[2] + ss[3];
    sq = sqs[0] + sqs[1] + sqs[2] + sqs[3];
    const float mean = s * (1.0f / PDIM);
    const float var  = sq * (1.0f / PDIM) - mean * mean;
    const float rstd = rsqrtf(var + 1e-5f);
    znb[row * PDIM + tid] = f2bs((v - mean) * rstd * g[tid] + b[tid]);
}

// ---------------------------------------------------------------------------
// MFMA flash attention + epilogue t = ao*alpha + z  (bf16 out).
// Grid (L/64, B*H), 256 thr = 4 waves; wave owns 16 q-rows.
// Swapped QK^T: S^T[key][q] = K·Q^T so softmax reduce = regs + shfl_xor(16,32).
// ---------------------------------------------------------------------------
__global__ __launch_bounds__(256) void attn_mfma(
    const ushort* __restrict__ znb, const ushort* __restrict__ kvb,
    const float* __restrict__ zres, const float* __restrict__ alpha_p,
    ushort* __restrict__ tb)
{
    const int b = blockIdx.y >> 2, h = blockIdx.y & 3;
    const int q0 = blockIdx.x * 64;
    const int tid = threadIdx.x;
    const int l = tid & 63, w = tid >> 6;
    const int lg = l >> 4, lr = l & 15;

    __shared__ ushort Ks[64 * 64];      // [key][dim], 16B-slot swizzled
    __shared__ ushort Vt[64 * 72];      // [dim][key], padded stride 72
    __shared__ ushort Pt[4][16 * 64];   // per-wave P[q][key], swizzled

    const long qrow = (long)b * L_SEQ + q0 + w * 16 + lr;
    const sv8 qf0 = *(const sv8*)&znb[qrow * PDIM + h * 64 + lg * 8];
    const sv8 qf1 = *(const sv8*)&znb[qrow * PDIM + h * 64 + 32 + lg * 8];

    float m_col = -3.0e38f, l_col = 0.0f;
    fv4 o_acc[4];
    #pragma unroll
    for (int nt = 0; nt < 4; nt++) o_acc[nt] = (fv4){0.f, 0.f, 0.f, 0.f};

    const ushort* kvh = kvb + (long)b * L_SEQ * 512 + h * 64;

    for (int kt = 0; kt < L_SEQ / 64; kt++) {
        __syncthreads();
        #pragma unroll
        for (int i = 0; i < 2; i++) {            // K straight, swizzled
            int s = tid + i * 256;
            int r = s >> 3, sl = s & 7;
            sv8 v = *(const sv8*)&kvh[(long)(kt * 64 + r) * 512 + sl * 8];
            *(sv8*)&Ks[r * 64 + ((sl ^ (r & 7)) * 8)] = v;
        }
        #pragma unroll
        for (int i = 0; i < 2; i++) {            // V transposed (rotated scatter)
            int s = tid + i * 256;
            int key = s >> 3, dblk = s & 7;
            sv8 v = *(const sv8*)&kvh[(long)(kt * 64 + key) * 512 + 256 + dblk * 8];
            #pragma unroll
            for (int j = 0; j < 8; j++) {
                int jj = (j + dblk) & 7;         // vary dim&7 across lanes per inst
                Vt[(dblk * 8 + jj) * 72 + key] = ((const ushort*)&v)[jj];
            }
        }
        __syncthreads();

        // S^T = K · Q^T   (4 key-tiles x K=64)
        fv4 st[4];
        __builtin_amdgcn_s_setprio(1);
        #pragma unroll
        for (int mt = 0; mt < 4; mt++) {
            st[mt] = (fv4){0.f, 0.f, 0.f, 0.f};
            int r = mt * 16 + lr;
            sv8 ka0 = *(const sv8*)&Ks[r * 64 + ((lg ^ (r & 7)) * 8)];
            sv8 ka1 = *(const sv8*)&Ks[r * 64 + (((4 + lg) ^ (r & 7)) * 8)];
            st[mt] = __builtin_amdgcn_mfma_f32_16x16x32_bf16(ka0, qf0, st[mt], 0, 0, 0);
            st[mt] = __builtin_amdgcn_mfma_f32_16x16x32_bf16(ka1, qf1, st[mt], 0, 0, 0);
        }
        __builtin_amdgcn_s_setprio(0);
        // online softmax (per q-col = lr)
        float mx = m_col;
        #pragma unroll
        for (int mt = 0; mt < 4; mt++)
            #pragma unroll
            for (int e = 0; e < 4; e++)
                mx = fmaxf(mx, st[mt][e] * 0.125f);
        mx = fmaxf(mx, __shfl_xor(mx, 16));
        mx = fmaxf(mx, __shfl_xor(mx, 32));
        float ps = 0.f;
        #pragma unroll
        for (int mt = 0; mt < 4; mt++)
            #pragma unroll
            for (int e = 0; e < 4; e++) {
                float p = __expf(st[mt][e] * 0.125f - mx);
                st[mt][e] = p;
                ps += p;
            }
        float rs = __expf(m_col - mx);
        ps += __shfl_xor(ps, 16);
        ps += __shfl_xor(ps, 32);
        l_col = l_col * rs + ps;
        m_col = mx;
        // P -> per-wave LDS (bf16) in A-frag layout
        #pragma unroll
        for (int mt = 0; mt < 4; mt++) {
            sv4 pw;
            pw[0] = f2bs(st[mt][0]); pw[1] = f2bs(st[mt][1]);
            pw[2] = f2bs(st[mt][2]); pw[3] = f2bs(st[mt][3]);
            int slot = 2 * mt + (lg >> 1);
            int idx = lr * 64 + ((slot ^ (lr & 7)) * 8) + 4 * (lg & 1);
            *(sv4*)&Pt[w][idx] = pw;
        }
        // O rescale (rows are q: fetch rs for q = lg*4+e from lane q)
        float rs_row[4];
        #pragma unroll
        for (int e = 0; e < 4; e++) rs_row[e] = __shfl(rs, lg * 4 + e);
        #pragma unroll
        for (int nt = 0; nt < 4; nt++)
            #pragma unroll
            for (int e = 0; e < 4; e++)
                o_acc[nt][e] *= rs_row[e];
        // O += P @ V
        __builtin_amdgcn_s_setprio(1);
        #pragma unroll
        for (int kk = 0; kk < 2; kk++) {
            sv8 pa = *(const sv8*)&Pt[w][lr * 64 + (((kk * 4 + lg) ^ (lr & 7)) * 8)];
            #pragma unroll
            for (int nt = 0; nt < 4; nt++) {
                int dim = nt * 16 + lr;
                sv8 vb = *(const sv8*)&Vt[dim * 72 + kk * 32 + lg * 8];
                o_acc[nt] = __builtin_amdgcn_mfma_f32_16x16x32_bf16(pa, vb, o_acc[nt], 0, 0, 0);
            }
        }
        __builtin_amdgcn_s_setprio(0);
    }
    float linv = 1.0f / l_col;
    float li_row[4];
    #pragma unroll
    for (int e = 0; e < 4; e++) li_row[e] = __shfl(linv, lg * 4 + e);
    const float a = alpha_p[0];
    #pragma unroll
    for (int nt = 0; nt < 4; nt++)
        #pragma unroll
        for (int e = 0; e < 4; e++) {
            long row = (long)b * L_SEQ + q0 + w * 16 + lg * 4 + e;
            int col = h * 64 + nt * 16 + lr;
            float t = o_acc[nt][e] * li_row[e] * a + zres[row * PDIM + col];
            tb[row * PDIM + col] = f2bs(t);
        }
}

// ---------------------------------------------------------------------------
// f32 -> bf16 cast (x -> hb), 4 elems/thread.
// ---------------------------------------------------------------------------
__global__ __launch_bounds__(256) void cast_bf16(
    const float* __restrict__ in, ushort* __restrict__ out)
{
    long i = (long)blockIdx.x * 256 + threadIdx.x;
    float4 v = ((const float4*)in)[i];
    sv4 o;
    o[0] = f2bs(v.x); o[1] = f2bs(v.y); o[2] = f2bs(v.z); o[3] = f2bs(v.w);
    *(sv4*)&out[i * 4] = o;
}

// ---------------------------------------------------------------------------
// Weight transpose + cast: W[K][N] f32 -> Wt[N][K] bf16 (32x32 tiles).
// ---------------------------------------------------------------------------
__global__ __launch_bounds__(256) void tcast(
    const float* __restrict__ W, ushort* __restrict__ Wt, int K, int N)
{
    __shared__ float t[32][33];
    const int n0 = blockIdx.x * 32, k0 = blockIdx.y * 32;
    const int c = threadIdx.x & 31, r = threadIdx.x >> 5;
    #pragma unroll
    for (int i = 0; i < 4; i++)
        t[r + i * 8][c] = W[(long)(k0 + r + i * 8) * N + n0 + c];
    __syncthreads();
    #pragma unroll
    for (int i = 0; i < 4; i++)
        Wt[(long)(n0 + r + i * 8) * K + k0 + c] = f2bs(t[c][r + i * 8]);
}

// ---------------------------------------------------------------------------
// SRU recurrence over one SCHUNK of 512 timesteps. bf16 U input.
// 64 blocks x 64 threads (one channel each) -> 64 CUs issuing loads.
// Unroll-8 register double-buffer: batch t+8's loads issue during batch t's
// serial compute chain (~320 cyc) -> L2/L3 latency hidden.
// cstate = c_finals region of d_out; chunk 0 seeds from c0 (deterministic).
// ---------------------------------------------------------------------------
__global__ __launch_bounds__(64) void scan_chunk(
    const ushort* __restrict__ Uc, const float* __restrict__ xin,
    float* __restrict__ hout, ushort* __restrict__ hb,
    float* __restrict__ cstate, const float* __restrict__ c0,
    const float* __restrict__ wcl, const float* __restrict__ biasl, int chunk)
{
    const int gid = blockIdx.x * 64 + threadIdx.x;   // 0..4095
    const int b = gid >> 10, ch = gid & 1023;
    const float vf = wcl[ch],   vr = wcl[DMODEL + ch];
    const float bf = biasl[ch], br = biasl[DMODEL + ch];
    float c = (chunk == 0) ? c0[gid] : cstate[gid];
    const ushort* u = Uc + (long)b * SCHUNK * 3072 + ch;
    const long xoff = (long)b * L_SEQ * DMODEL + (long)chunk * SCHUNK * DMODEL + ch;
    const float* x = xin + xoff;
    float* hp = hout + xoff;
    ushort* hbp = hb + xoff;

    ushort a0[8], a1[8], a2[8];
    float  ax[8];
    #pragma unroll
    for (int j = 0; j < 8; j++) {
        a0[j] = u[(long)j * 3072];
        a1[j] = u[(long)j * 3072 + 1024];
        a2[j] = u[(long)j * 3072 + 2048];
        ax[j] = x[(long)j * 1024];
    }
    for (int t0 = 0; t0 < SCHUNK; t0 += 8) {
        ushort n0[8], n1[8], n2[8];
        float  nx[8];
        if (t0 + 8 < SCHUNK) {
            const ushort* un = u + (long)(t0 + 8) * 3072;
            const float*  xn = x + (long)(t0 + 8) * 1024;
            #pragma unroll
            for (int j = 0; j < 8; j++) {
                n0[j] = un[(long)j * 3072];
                n1[j] = un[(long)j * 3072 + 1024];
                n2[j] = un[(long)j * 3072 + 2048];
                nx[j] = xn[(long)j * 1024];
            }
        }
        #pragma unroll
        for (int j = 0; j < 8; j++) {
            float u0 = bs2f(a0[j]), u1 = bs2f(a1[j]), u2 = bs2f(a2[j]);
            float xv = ax[j];
            float f = sigmoidf_(u1 + bf + vf * c);
            c = u0 + (c - u0) * f;
            float r = sigmoidf_(u2 + br + vr * c);
            float hv = (c - xv) * r + xv;
            hp[(long)(t0 + j) * 1024]  = hv;
            hbp[(long)(t0 + j) * 1024] = f2bs(hv);
        }
        #pragma unroll
        for (int j = 0; j < 8; j++) {
            a0[j] = n0[j]; a1[j] = n1[j]; a2[j] = n2[j]; ax[j] = nx[j];
        }
    }
    cstate[gid] = c;
}

// ---------------------------------------------------------------------------
extern "C" void kernel_launch(void* const* d_in, const int* in_sizes, int n_in,
                              void* d_out, int out_size, void* d_ws, size_t ws_size,
                              hipStream_t stream)
{
    const float* x     = (const float*)d_in[0];
    const float* W1    = (const float*)d_in[1];
    const float* ln_g  = (const float*)d_in[2];
    const float* ln_b  = (const float*)d_in[3];
    const float* W2    = (const float*)d_in[4];
    const float* alpha = (const float*)d_in[5];
    const float* W3    = (const float*)d_in[6];
    const float* wc    = (const float*)d_in[7];
    const float* bias  = (const float*)d_in[8];
    const float* c0    = (const float*)d_in[9];

    float* hout = (float*)d_out;                              // (B,L,D)
    float* cout = hout + (long)BATCH * L_SEQ * DMODEL;        // (nl,B,D)

    // ws layout (44.3 MB total; bf16 Uc overlays dead znb+kvb exactly: 12.58 MB)
    ushort* hb   = (ushort*)d_ws;                             // 16.8 MB  bf16 h
    float*  z    = (float*)(hb + (long)8192 * 1024);          // 8.4 MB
    ushort* znb  = (ushort*)(z + (long)8192 * 256);           // 4.2 MB
    ushort* kvb  = znb + (long)8192 * 256;                    // 8.4 MB
    ushort* tbuf = kvb + (long)8192 * 512;                    // 4.2 MB
    ushort* W1t  = tbuf + (long)8192 * 256;                   // 0.5 MB
    ushort* W2t  = W1t + 256 * 1024;                          // 0.25 MB
    ushort* W3t  = W2t + 512 * 256;                           // 1.5 MB
    ushort* Uc   = znb;   // bf16, 4*512*3072*2 B = znb+kvb region exactly

    // x -> bf16 (8192*1024 elems, 4/thread)
    cast_bf16<<<8192, 256, 0, stream>>>(x, hb);

    for (int l = 0; l < NLAYERS; l++) {
        // weights -> transposed bf16 [N][K]
        tcast<<<dim3(PDIM / 32, DMODEL / 32), 256, 0, stream>>>(
            W1 + (long)l * DMODEL * PDIM, W1t, DMODEL, PDIM);
        tcast<<<dim3(2 * PDIM / 32, PDIM / 32), 256, 0, stream>>>(
            W2 + (long)l * PDIM * 2 * PDIM, W2t, PDIM, 2 * PDIM);
        tcast<<<dim3(3 * DMODEL / 32, PDIM / 32), 256, 0, stream>>>(
            W3 + (long)l * PDIM * 3 * DMODEL, W3t, PDIM, 3 * DMODEL);

        // z = h @ W1   (8192 x 1024 -> 256), f32 out
        gemm_mfma<64, false><<<dim3(PDIM / 64, 8192 / 128, 1), 256, 0, stream>>>(
            hb, W1t, z, PDIM, DMODEL, 0, 0);

        // zn = LN(z) -> bf16
        ln_kernel<<<8192, 256, 0, stream>>>(z, ln_g + l * PDIM, ln_b + l * PDIM, znb);

        // kv = zn @ W2  (8192 x 256 -> 512), bf16 out
        gemm_mfma<128, true><<<dim3(512 / 128, 8192 / 128, 1), 256, 0, stream>>>(
            znb, W2t, kvb, 512, PDIM, 0, 0);

        // t = attn(zn)*alpha + z -> bf16
        attn_mfma<<<dim3(L_SEQ / 64, BATCH * NHEADS), 256, 0, stream>>>(
            znb, kvb, z, alpha + l, tbuf);

        // U = t @ W3 per 512-step chunk (bf16 out), then recurrence
        for (int cch = 0; cch < NCHUNK; cch++) {
            gemm_mfma<128, true><<<dim3(3072 / 128, SCHUNK / 128, BATCH), 256, 0, stream>>>(
                tbuf + (long)cch * SCHUNK * PDIM, W3t, Uc, 3072, PDIM,
                (long)L_SEQ * PDIM, (long)SCHUNK * 3072);
            scan_chunk<<<64, 64, 0, stream>>>(
                Uc, (l == 0) ? x : hout, hout, hb,
                cout + (long)l * BATCH * DMODEL, c0 + (long)l * BATCH * DMODEL,
                wc + (long)l * 2 * DMODEL, bias + (long)l * 2 * DMODEL, cch);
        }
    }
}

// Round 4
// 825.976 us; speedup vs baseline: 3.9071x; 1.6871x over previous
//
#include <hip/hip_runtime.h>
#include <hip/hip_bf16.h>

// SRU++ forward, MI355X. Round 4: U computed transposed -> lane-sequential scan reads.
// Shapes: B=4, L=2048, d=1024, p=256, H=4, hd=64, nl=2.
#define L_SEQ  2048
#define BATCH  4
#define DMODEL 1024
#define PDIM   256
#define NHEADS 4
#define HDIM   64
#define NLAYERS 2
#define SCHUNK 512
#define NCHUNK (L_SEQ / SCHUNK)

typedef __attribute__((ext_vector_type(8))) short sv8;   // 8 bf16 (4 VGPRs) MFMA A/B frag
typedef __attribute__((ext_vector_type(4))) short sv4;
typedef __attribute__((ext_vector_type(4))) float fv4;   // MFMA C/D frag

static __device__ __forceinline__ short f2bs(float f) {
    union { __hip_bfloat16 h; short s; } u;
    u.h = __float2bfloat16(f);
    return u.s;
}
static __device__ __forceinline__ float bs2f(ushort s) {
    union { float f; unsigned u; } v;
    v.u = ((unsigned)s) << 16;
    return v.f;
}
static __device__ __forceinline__ float sigmoidf_(float x) {
    return 1.0f / (1.0f + __expf(-x));
}

// ---------------------------------------------------------------------------
// bf16 MFMA GEMM: C[row][col] = sum_k A[row][k] * Bt[col][k].
// A: [M][K] row-major (M = gridDim.y*128), Bt: [N][K] row-major.
// C at (long)z*cStrideZ + row*ldc + col  (f32 or bf16).
// BM=128, BK=64, 256 threads = 4 waves (2x2), wave tile 64 x BN/2.
// LDS 16B-slot XOR swizzle (slot ^= row&7) -> conflict-free frag reads.
// C/D frag: col = l&15, row = (l>>4)*4 + reg  [learn_hip m89/m91].
// ---------------------------------------------------------------------------
template<int BN, bool OUT_BF16>
__global__ __launch_bounds__(256) void gemm_mfma(
    const ushort* __restrict__ A, const ushort* __restrict__ Bt,
    void* __restrict__ Cout, int K, int ldc,
    long aStrideZ, long bStrideZ, long cStrideZ)
{
    constexpr int BM = 128;
    constexpr int WN = BN / 2, NI = WN / 16;
    const ushort* Ag = A  + (long)blockIdx.z * aStrideZ;
    const ushort* Bg = Bt + (long)blockIdx.z * bStrideZ;
    const long row0 = (long)blockIdx.y * BM;
    const int col0 = blockIdx.x * BN;
    __shared__ ushort As[BM * 64];
    __shared__ ushort Bs[BN * 64];
    const int tid = threadIdx.x;
    const int l = tid & 63, w = tid >> 6;
    const int lg = l >> 4, lr = l & 15;
    const int wr = w >> 1, wc = w & 1;

    fv4 acc[4][NI];
    #pragma unroll
    for (int mi = 0; mi < 4; mi++)
        #pragma unroll
        for (int ni = 0; ni < NI; ni++)
            acc[mi][ni] = (fv4){0.f, 0.f, 0.f, 0.f};

    for (int k0 = 0; k0 < K; k0 += 64) {
        __syncthreads();
        #pragma unroll
        for (int i = 0; i < 4; i++) {            // A tile: 128x64
            int s = tid + i * 256;
            int r = s >> 3, sl = s & 7;
            sv8 v = *(const sv8*)&Ag[(row0 + r) * K + k0 + sl * 8];
            *(sv8*)&As[r * 64 + ((sl ^ (r & 7)) * 8)] = v;
        }
        #pragma unroll
        for (int i = 0; i < BN / 32; i++) {      // B tile: BNx64
            int s = tid + i * 256;
            int r = s >> 3, sl = s & 7;
            sv8 v = *(const sv8*)&Bg[(long)(col0 + r) * K + k0 + sl * 8];
            *(sv8*)&Bs[r * 64 + ((sl ^ (r & 7)) * 8)] = v;
        }
        __syncthreads();
        #pragma unroll
        for (int kk = 0; kk < 2; kk++) {
            sv8 af[4], bfr[NI];
            #pragma unroll
            for (int mi = 0; mi < 4; mi++) {
                int r = wr * 64 + mi * 16 + lr;
                af[mi] = *(const sv8*)&As[r * 64 + (((kk * 4 + lg) ^ (r & 7)) * 8)];
            }
            #pragma unroll
            for (int ni = 0; ni < NI; ni++) {
                int r = wc * WN + ni * 16 + lr;
                bfr[ni] = *(const sv8*)&Bs[r * 64 + (((kk * 4 + lg) ^ (r & 7)) * 8)];
            }
            __builtin_amdgcn_s_setprio(1);
            #pragma unroll
            for (int mi = 0; mi < 4; mi++)
                #pragma unroll
                for (int ni = 0; ni < NI; ni++)
                    acc[mi][ni] = __builtin_amdgcn_mfma_f32_16x16x32_bf16(
                        af[mi], bfr[ni], acc[mi][ni], 0, 0, 0);
            __builtin_amdgcn_s_setprio(0);
        }
    }
    #pragma unroll
    for (int mi = 0; mi < 4; mi++)
        #pragma unroll
        for (int ni = 0; ni < NI; ni++)
            #pragma unroll
            for (int e = 0; e < 4; e++) {
                long row = row0 + wr * 64 + mi * 16 + lg * 4 + e;
                int col = col0 + wc * WN + ni * 16 + lr;
                long idx = (long)blockIdx.z * cStrideZ + row * ldc + col;
                if (OUT_BF16) ((ushort*)Cout)[idx] = f2bs(acc[mi][ni][e]);
                else          ((float*)Cout)[idx]  = acc[mi][ni][e];
            }
}

// ---------------------------------------------------------------------------
// LayerNorm over p=256, one block/row; f32 in, bf16 out.
// ---------------------------------------------------------------------------
__global__ __launch_bounds__(256) void ln_kernel(
    const float* __restrict__ z, const float* __restrict__ g,
    const float* __restrict__ b, ushort* __restrict__ znb)
{
    const long row = blockIdx.x;
    const int tid = threadIdx.x;
    float v = z[row * PDIM + tid];
    float s = v, sq = v * v;
    #pragma unroll
    for (int o = 32; o > 0; o >>= 1) {
        s  += __shfl_down(s, o, 64);
        sq += __shfl_down(sq, o, 64);
    }
    __shared__ float ss[4], sqs[4];
    if ((tid & 63) == 0) { ss[tid >> 6] = s; sqs[tid >> 6] = sq; }
    __syncthreads();
    s  = ss[0] + ss[1] + ss[2] + ss[3];
    sq = sqs[0] + sqs[1] + sqs[2] + sqs[3];
    const float mean = s * (1.0f / PDIM);
    const float var  = sq * (1.0f / PDIM) - mean * mean;
    const float rstd = rsqrtf(var + 1e-5f);
    znb[row * PDIM + tid] = f2bs((v - mean) * rstd * g[tid] + b[tid]);
}

// ---------------------------------------------------------------------------
// MFMA flash attention + epilogue t = ao*alpha + z  (bf16 out).
// Grid (L/64, B*H), 256 thr = 4 waves; wave owns 16 q-rows.
// Swapped QK^T: S^T[key][q] = K·Q^T so softmax reduce = regs + shfl_xor(16,32).
// ---------------------------------------------------------------------------
__global__ __launch_bounds__(256) void attn_mfma(
    const ushort* __restrict__ znb, const ushort* __restrict__ kvb,
    const float* __restrict__ zres, const float* __restrict__ alpha_p,
    ushort* __restrict__ tb)
{
    const int b = blockIdx.y >> 2, h = blockIdx.y & 3;
    const int q0 = blockIdx.x * 64;
    const int tid = threadIdx.x;
    const int l = tid & 63, w = tid >> 6;
    const int lg = l >> 4, lr = l & 15;

    __shared__ ushort Ks[64 * 64];      // [key][dim], 16B-slot swizzled
    __shared__ ushort Vt[64 * 72];      // [dim][key], padded stride 72
    __shared__ ushort Pt[4][16 * 64];   // per-wave P[q][key], swizzled

    const long qrow = (long)b * L_SEQ + q0 + w * 16 + lr;
    const sv8 qf0 = *(const sv8*)&znb[qrow * PDIM + h * 64 + lg * 8];
    const sv8 qf1 = *(const sv8*)&znb[qrow * PDIM + h * 64 + 32 + lg * 8];

    float m_col = -3.0e38f, l_col = 0.0f;
    fv4 o_acc[4];
    #pragma unroll
    for (int nt = 0; nt < 4; nt++) o_acc[nt] = (fv4){0.f, 0.f, 0.f, 0.f};

    const ushort* kvh = kvb + (long)b * L_SEQ * 512 + h * 64;

    for (int kt = 0; kt < L_SEQ / 64; kt++) {
        __syncthreads();
        #pragma unroll
        for (int i = 0; i < 2; i++) {            // K straight, swizzled
            int s = tid + i * 256;
            int r = s >> 3, sl = s & 7;
            sv8 v = *(const sv8*)&kvh[(long)(kt * 64 + r) * 512 + sl * 8];
            *(sv8*)&Ks[r * 64 + ((sl ^ (r & 7)) * 8)] = v;
        }
        #pragma unroll
        for (int i = 0; i < 2; i++) {            // V transposed (rotated scatter)
            int s = tid + i * 256;
            int key = s >> 3, dblk = s & 7;
            sv8 v = *(const sv8*)&kvh[(long)(kt * 64 + key) * 512 + 256 + dblk * 8];
            #pragma unroll
            for (int j = 0; j < 8; j++) {
                int jj = (j + dblk) & 7;         // vary dim&7 across lanes per inst
                Vt[(dblk * 8 + jj) * 72 + key] = ((const ushort*)&v)[jj];
            }
        }
        __syncthreads();

        // S^T = K · Q^T   (4 key-tiles x K=64)
        fv4 st[4];
        __builtin_amdgcn_s_setprio(1);
        #pragma unroll
        for (int mt = 0; mt < 4; mt++) {
            st[mt] = (fv4){0.f, 0.f, 0.f, 0.f};
            int r = mt * 16 + lr;
            sv8 ka0 = *(const sv8*)&Ks[r * 64 + ((lg ^ (r & 7)) * 8)];
            sv8 ka1 = *(const sv8*)&Ks[r * 64 + (((4 + lg) ^ (r & 7)) * 8)];
            st[mt] = __builtin_amdgcn_mfma_f32_16x16x32_bf16(ka0, qf0, st[mt], 0, 0, 0);
            st[mt] = __builtin_amdgcn_mfma_f32_16x16x32_bf16(ka1, qf1, st[mt], 0, 0, 0);
        }
        __builtin_amdgcn_s_setprio(0);
        // online softmax (per q-col = lr)
        float mx = m_col;
        #pragma unroll
        for (int mt = 0; mt < 4; mt++)
            #pragma unroll
            for (int e = 0; e < 4; e++)
                mx = fmaxf(mx, st[mt][e] * 0.125f);
        mx = fmaxf(mx, __shfl_xor(mx, 16));
        mx = fmaxf(mx, __shfl_xor(mx, 32));
        float ps = 0.f;
        #pragma unroll
        for (int mt = 0; mt < 4; mt++)
            #pragma unroll
            for (int e = 0; e < 4; e++) {
                float p = __expf(st[mt][e] * 0.125f - mx);
                st[mt][e] = p;
                ps += p;
            }
        float rs = __expf(m_col - mx);
        ps += __shfl_xor(ps, 16);
        ps += __shfl_xor(ps, 32);
        l_col = l_col * rs + ps;
        m_col = mx;
        // P -> per-wave LDS (bf16) in A-frag layout
        #pragma unroll
        for (int mt = 0; mt < 4; mt++) {
            sv4 pw;
            pw[0] = f2bs(st[mt][0]); pw[1] = f2bs(st[mt][1]);
            pw[2] = f2bs(st[mt][2]); pw[3] = f2bs(st[mt][3]);
            int slot = 2 * mt + (lg >> 1);
            int idx = lr * 64 + ((slot ^ (lr & 7)) * 8) + 4 * (lg & 1);
            *(sv4*)&Pt[w][idx] = pw;
        }
        // O rescale (rows are q: fetch rs for q = lg*4+e from lane q)
        float rs_row[4];
        #pragma unroll
        for (int e = 0; e < 4; e++) rs_row[e] = __shfl(rs, lg * 4 + e);
        #pragma unroll
        for (int nt = 0; nt < 4; nt++)
            #pragma unroll
            for (int e = 0; e < 4; e++)
                o_acc[nt][e] *= rs_row[e];
        // O += P @ V
        __builtin_amdgcn_s_setprio(1);
        #pragma unroll
        for (int kk = 0; kk < 2; kk++) {
            sv8 pa = *(const sv8*)&Pt[w][lr * 64 + (((kk * 4 + lg) ^ (lr & 7)) * 8)];
            #pragma unroll
            for (int nt = 0; nt < 4; nt++) {
                int dim = nt * 16 + lr;
                sv8 vb = *(const sv8*)&Vt[dim * 72 + kk * 32 + lg * 8];
                o_acc[nt] = __builtin_amdgcn_mfma_f32_16x16x32_bf16(pa, vb, o_acc[nt], 0, 0, 0);
            }
        }
        __builtin_amdgcn_s_setprio(0);
    }
    float linv = 1.0f / l_col;
    float li_row[4];
    #pragma unroll
    for (int e = 0; e < 4; e++) li_row[e] = __shfl(linv, lg * 4 + e);
    const float a = alpha_p[0];
    #pragma unroll
    for (int nt = 0; nt < 4; nt++)
        #pragma unroll
        for (int e = 0; e < 4; e++) {
            long row = (long)b * L_SEQ + q0 + w * 16 + lg * 4 + e;
            int col = h * 64 + nt * 16 + lr;
            float t = o_acc[nt][e] * li_row[e] * a + zres[row * PDIM + col];
            tb[row * PDIM + col] = f2bs(t);
        }
}

// ---------------------------------------------------------------------------
// f32 -> bf16 cast (x -> hb), 4 elems/thread.
// ---------------------------------------------------------------------------
__global__ __launch_bounds__(256) void cast_bf16(
    const float* __restrict__ in, ushort* __restrict__ out)
{
    long i = (long)blockIdx.x * 256 + threadIdx.x;
    float4 v = ((const float4*)in)[i];
    sv4 o;
    o[0] = f2bs(v.x); o[1] = f2bs(v.y); o[2] = f2bs(v.z); o[3] = f2bs(v.w);
    *(sv4*)&out[i * 4] = o;
}

// ---------------------------------------------------------------------------
// Weight transpose + cast: W[K][N] f32 -> Wt[N][K] bf16 (32x32 tiles).
// ---------------------------------------------------------------------------
__global__ __launch_bounds__(256) void tcast(
    const float* __restrict__ W, ushort* __restrict__ Wt, int K, int N)
{
    __shared__ float t[32][33];
    const int n0 = blockIdx.x * 32, k0 = blockIdx.y * 32;
    const int c = threadIdx.x & 31, r = threadIdx.x >> 5;
    #pragma unroll
    for (int i = 0; i < 4; i++)
        t[r + i * 8][c] = W[(long)(k0 + r + i * 8) * N + n0 + c];
    __syncthreads();
    #pragma unroll
    for (int i = 0; i < 4; i++)
        Wt[(long)(n0 + r + i * 8) * K + k0 + c] = f2bs(t[c][r + i * 8]);
}

// ---------------------------------------------------------------------------
// SRU recurrence over one SCHUNK of 512 timesteps, TRANSPOSED U input:
// Ut[ch][b*512 + t] (ch in [0,3072): u0 rows 0..1023, u1 1024.., u2 2048..).
// Each lane walks its own Ut rows sequentially -> L1-resident after first
// touch of each 128B line (64 steps). 16-step register prefetch covers the
// per-line refill. 64 blocks x 64 threads = (b, ch) channels.
// cstate = c_finals region of d_out; chunk 0 seeds from c0 (deterministic).
// ---------------------------------------------------------------------------
__global__ __launch_bounds__(64) void scan_chunk_t(
    const ushort* __restrict__ Ut, const float* __restrict__ xin,
    float* __restrict__ hout, ushort* __restrict__ hb,
    float* __restrict__ cstate, const float* __restrict__ c0,
    const float* __restrict__ wcl, const float* __restrict__ biasl, int chunk)
{
    const int gid = blockIdx.x * 64 + threadIdx.x;   // 0..4095
    const int b = gid >> 10, ch = gid & 1023;
    const float vf = wcl[ch],    vr = wcl[DMODEL + ch];
    const float bfc = biasl[ch], brc = biasl[DMODEL + ch];
    float c = (chunk == 0) ? c0[gid] : cstate[gid];
    const ushort* u0p = Ut + (long)ch * (BATCH * SCHUNK) + b * SCHUNK;
    const ushort* u1p = u0p + (long)1024 * (BATCH * SCHUNK);
    const ushort* u2p = u0p + (long)2048 * (BATCH * SCHUNK);
    const long xoff = (long)b * L_SEQ * DMODEL + (long)chunk * SCHUNK * DMODEL + ch;
    const float* xp = xin + xoff;
    float* hp = hout + xoff;
    ushort* hbp = hb + xoff;

    sv8 cu0[2], cu1[2], cu2[2];
    float cx[16];
    #pragma unroll
    for (int q = 0; q < 2; q++) {
        cu0[q] = *(const sv8*)&u0p[q * 8];
        cu1[q] = *(const sv8*)&u1p[q * 8];
        cu2[q] = *(const sv8*)&u2p[q * 8];
    }
    #pragma unroll
    for (int j = 0; j < 16; j++) cx[j] = xp[(long)j * DMODEL];

    for (int t0 = 0; t0 < SCHUNK; t0 += 16) {
        sv8 n0[2], n1[2], n2[2];
        float nx[16];
        const bool more = (t0 + 16 < SCHUNK);
        if (more) {
            #pragma unroll
            for (int q = 0; q < 2; q++) {
                n0[q] = *(const sv8*)&u0p[t0 + 16 + q * 8];
                n1[q] = *(const sv8*)&u1p[t0 + 16 + q * 8];
                n2[q] = *(const sv8*)&u2p[t0 + 16 + q * 8];
            }
            #pragma unroll
            for (int j = 0; j < 16; j++) nx[j] = xp[(long)(t0 + 16 + j) * DMODEL];
        }
        #pragma unroll
        for (int j = 0; j < 16; j++) {
            float u0 = bs2f((ushort)cu0[j >> 3][j & 7]);
            float u1 = bs2f((ushort)cu1[j >> 3][j & 7]);
            float u2 = bs2f((ushort)cu2[j >> 3][j & 7]);
            float xv = cx[j];
            float f = sigmoidf_(u1 + bfc + vf * c);
            c = u0 + (c - u0) * f;
            float r = sigmoidf_(u2 + brc + vr * c);
            float hv = (c - xv) * r + xv;
            hp[(long)(t0 + j) * DMODEL]  = hv;
            hbp[(long)(t0 + j) * DMODEL] = f2bs(hv);
        }
        if (more) {
            #pragma unroll
            for (int q = 0; q < 2; q++) {
                cu0[q] = n0[q]; cu1[q] = n1[q]; cu2[q] = n2[q];
            }
            #pragma unroll
            for (int j = 0; j < 16; j++) cx[j] = nx[j];
        }
    }
    cstate[gid] = c;
}

// ---------------------------------------------------------------------------
extern "C" void kernel_launch(void* const* d_in, const int* in_sizes, int n_in,
                              void* d_out, int out_size, void* d_ws, size_t ws_size,
                              hipStream_t stream)
{
    const float* x     = (const float*)d_in[0];
    const float* W1    = (const float*)d_in[1];
    const float* ln_g  = (const float*)d_in[2];
    const float* ln_b  = (const float*)d_in[3];
    const float* W2    = (const float*)d_in[4];
    const float* alpha = (const float*)d_in[5];
    const float* W3    = (const float*)d_in[6];
    const float* wc    = (const float*)d_in[7];
    const float* bias  = (const float*)d_in[8];
    const float* c0    = (const float*)d_in[9];

    float* hout = (float*)d_out;                              // (B,L,D)
    float* cout = hout + (long)BATCH * L_SEQ * DMODEL;        // (nl,B,D)

    // ws layout (44.3 MB; bf16 Ut overlays dead znb+kvb exactly: 12.58 MB)
    ushort* hb   = (ushort*)d_ws;                             // 16.8 MB  bf16 h
    float*  z    = (float*)(hb + (long)8192 * 1024);          // 8.4 MB
    ushort* znb  = (ushort*)(z + (long)8192 * 256);           // 4.2 MB
    ushort* kvb  = znb + (long)8192 * 256;                    // 8.4 MB
    ushort* tbuf = kvb + (long)8192 * 512;                    // 4.2 MB
    ushort* W1t  = tbuf + (long)8192 * 256;                   // 0.5 MB
    ushort* W2t  = W1t + 256 * 1024;                          // 0.25 MB
    ushort* W3t  = W2t + 512 * 256;                           // 1.5 MB
    ushort* Ut   = znb;   // bf16 [3072][B*512] = 12.58 MB, fits znb+kvb

    // x -> bf16 (8192*1024 elems, 4/thread)
    cast_bf16<<<8192, 256, 0, stream>>>(x, hb);

    for (int l = 0; l < NLAYERS; l++) {
        // weights -> transposed bf16 [N][K]
        tcast<<<dim3(PDIM / 32, DMODEL / 32), 256, 0, stream>>>(
            W1 + (long)l * DMODEL * PDIM, W1t, DMODEL, PDIM);
        tcast<<<dim3(2 * PDIM / 32, PDIM / 32), 256, 0, stream>>>(
            W2 + (long)l * PDIM * 2 * PDIM, W2t, PDIM, 2 * PDIM);
        tcast<<<dim3(3 * DMODEL / 32, PDIM / 32), 256, 0, stream>>>(
            W3 + (long)l * PDIM * 3 * DMODEL, W3t, PDIM, 3 * DMODEL);

        // z = h @ W1   (8192 x 1024 -> 256), f32 out
        gemm_mfma<64, false><<<dim3(PDIM / 64, 8192 / 128, 1), 256, 0, stream>>>(
            hb, W1t, z, DMODEL, PDIM, 0, 0, 0);

        // zn = LN(z) -> bf16
        ln_kernel<<<8192, 256, 0, stream>>>(z, ln_g + l * PDIM, ln_b + l * PDIM, znb);

        // kv = zn @ W2  (8192 x 256 -> 512), bf16 out
        gemm_mfma<128, true><<<dim3(512 / 128, 8192 / 128, 1), 256, 0, stream>>>(
            znb, W2t, kvb, PDIM, 512, 0, 0, 0);

        // t = attn(zn)*alpha + z -> bf16
        attn_mfma<<<dim3(L_SEQ / 64, BATCH * NHEADS), 256, 0, stream>>>(
            znb, kvb, z, alpha + l, tbuf);

        // U^T = W3t @ t^T per 512-chunk:  Ut[m][b*512+t], m in [0,3072)
        //   A = W3t [3072][256], Bt = t-chunk rows [512][256] (batch-strided)
        for (int cch = 0; cch < NCHUNK; cch++) {
            gemm_mfma<128, true><<<dim3(SCHUNK / 128, 3072 / 128, BATCH), 256, 0, stream>>>(
                W3t, tbuf + (long)cch * SCHUNK * PDIM, Ut, PDIM, BATCH * SCHUNK,
                0, (long)L_SEQ * PDIM, SCHUNK);
            scan_chunk_t<<<64, 64, 0, stream>>>(
                Ut, (l == 0) ? x : hout, hout, hb,
                cout + (long)l * BATCH * DMODEL, c0 + (long)l * BATCH * DMODEL,
                wc + (long)l * 2 * DMODEL, bias + (long)l * 2 * DMODEL, cch);
        }
    }
}

// Round 5
// 643.403 us; speedup vs baseline: 5.0158x; 1.2838x over previous
//
#include <hip/hip_runtime.h>
#include <hip/hip_bf16.h>

// SRU++ forward, MI355X. Round 5: deep-prefetch bf16 scan + 128-q attention tiles.
// Shapes: B=4, L=2048, d=1024, p=256, H=4, hd=64, nl=2.
#define L_SEQ  2048
#define BATCH  4
#define DMODEL 1024
#define PDIM   256
#define NHEADS 4
#define HDIM   64
#define NLAYERS 2
#define SCHUNK 512
#define NCHUNK (L_SEQ / SCHUNK)

typedef __attribute__((ext_vector_type(8))) short sv8;   // 8 bf16 (4 VGPRs) MFMA A/B frag
typedef __attribute__((ext_vector_type(4))) short sv4;
typedef __attribute__((ext_vector_type(4))) float fv4;   // MFMA C/D frag

static __device__ __forceinline__ short f2bs(float f) {
    union { __hip_bfloat16 h; short s; } u;
    u.h = __float2bfloat16(f);
    return u.s;
}
static __device__ __forceinline__ float bs2f(ushort s) {
    union { float f; unsigned u; } v;
    v.u = ((unsigned)s) << 16;
    return v.f;
}

// ---------------------------------------------------------------------------
// bf16 MFMA GEMM: C[row][col] = sum_k A[row][k] * Bt[col][k].
// A: [M][K] row-major, Bt: [N][K] row-major.  C f32 or bf16.
// BM=128, BK=64, 256 threads = 4 waves (2x2), wave tile 64 x BN/2.
// LDS 16B-slot XOR swizzle (slot ^= row&7) -> conflict-free frag reads.
// C/D frag: col = l&15, row = (l>>4)*4 + reg  [learn_hip m89/m91].
// ---------------------------------------------------------------------------
template<int BN, bool OUT_BF16>
__global__ __launch_bounds__(256) void gemm_mfma(
    const ushort* __restrict__ A, const ushort* __restrict__ Bt,
    void* __restrict__ Cout, int K, int ldc,
    long aStrideZ, long bStrideZ, long cStrideZ)
{
    constexpr int BM = 128;
    constexpr int WN = BN / 2, NI = WN / 16;
    const ushort* Ag = A  + (long)blockIdx.z * aStrideZ;
    const ushort* Bg = Bt + (long)blockIdx.z * bStrideZ;
    const long row0 = (long)blockIdx.y * BM;
    const int col0 = blockIdx.x * BN;
    __shared__ ushort As[BM * 64];
    __shared__ ushort Bs[BN * 64];
    const int tid = threadIdx.x;
    const int l = tid & 63, w = tid >> 6;
    const int lg = l >> 4, lr = l & 15;
    const int wr = w >> 1, wc = w & 1;

    fv4 acc[4][NI];
    #pragma unroll
    for (int mi = 0; mi < 4; mi++)
        #pragma unroll
        for (int ni = 0; ni < NI; ni++)
            acc[mi][ni] = (fv4){0.f, 0.f, 0.f, 0.f};

    for (int k0 = 0; k0 < K; k0 += 64) {
        __syncthreads();
        #pragma unroll
        for (int i = 0; i < 4; i++) {            // A tile: 128x64
            int s = tid + i * 256;
            int r = s >> 3, sl = s & 7;
            sv8 v = *(const sv8*)&Ag[(row0 + r) * K + k0 + sl * 8];
            *(sv8*)&As[r * 64 + ((sl ^ (r & 7)) * 8)] = v;
        }
        #pragma unroll
        for (int i = 0; i < BN / 32; i++) {      // B tile: BNx64
            int s = tid + i * 256;
            int r = s >> 3, sl = s & 7;
            sv8 v = *(const sv8*)&Bg[(long)(col0 + r) * K + k0 + sl * 8];
            *(sv8*)&Bs[r * 64 + ((sl ^ (r & 7)) * 8)] = v;
        }
        __syncthreads();
        #pragma unroll
        for (int kk = 0; kk < 2; kk++) {
            sv8 af[4], bfr[NI];
            #pragma unroll
            for (int mi = 0; mi < 4; mi++) {
                int r = wr * 64 + mi * 16 + lr;
                af[mi] = *(const sv8*)&As[r * 64 + (((kk * 4 + lg) ^ (r & 7)) * 8)];
            }
            #pragma unroll
            for (int ni = 0; ni < NI; ni++) {
                int r = wc * WN + ni * 16 + lr;
                bfr[ni] = *(const sv8*)&Bs[r * 64 + (((kk * 4 + lg) ^ (r & 7)) * 8)];
            }
            __builtin_amdgcn_s_setprio(1);
            #pragma unroll
            for (int mi = 0; mi < 4; mi++)
                #pragma unroll
                for (int ni = 0; ni < NI; ni++)
                    acc[mi][ni] = __builtin_amdgcn_mfma_f32_16x16x32_bf16(
                        af[mi], bfr[ni], acc[mi][ni], 0, 0, 0);
            __builtin_amdgcn_s_setprio(0);
        }
    }
    #pragma unroll
    for (int mi = 0; mi < 4; mi++)
        #pragma unroll
        for (int ni = 0; ni < NI; ni++)
            #pragma unroll
            for (int e = 0; e < 4; e++) {
                long row = row0 + wr * 64 + mi * 16 + lg * 4 + e;
                int col = col0 + wc * WN + ni * 16 + lr;
                long idx = (long)blockIdx.z * cStrideZ + row * ldc + col;
                if (OUT_BF16) ((ushort*)Cout)[idx] = f2bs(acc[mi][ni][e]);
                else          ((float*)Cout)[idx]  = acc[mi][ni][e];
            }
}

// ---------------------------------------------------------------------------
// LayerNorm over p=256, one block/row; f32 in, bf16 out.
// ---------------------------------------------------------------------------
__global__ __launch_bounds__(256) void ln_kernel(
    const float* __restrict__ z, const float* __restrict__ g,
    const float* __restrict__ b, ushort* __restrict__ znb)
{
    const long row = blockIdx.x;
    const int tid = threadIdx.x;
    float v = z[row * PDIM + tid];
    float s = v, sq = v * v;
    #pragma unroll
    for (int o = 32; o > 0; o >>= 1) {
        s  += __shfl_down(s, o, 64);
        sq += __shfl_down(sq, o, 64);
    }
    __shared__ float ss[4], sqs[4];
    if ((tid & 63) == 0) { ss[tid >> 6] = s; sqs[tid >> 6] = sq; }
    __syncthreads();
    s  = ss[0] + ss[1] + ss[2] + ss[3];
    sq = sqs[0] + sqs[1] + sqs[2] + sqs[3];
    const float mean = s * (1.0f / PDIM);
    const float var  = sq * (1.0f / PDIM) - mean * mean;
    const float rstd = rsqrtf(var + 1e-5f);
    znb[row * PDIM + tid] = f2bs((v - mean) * rstd * g[tid] + b[tid]);
}

// ---------------------------------------------------------------------------
// MFMA flash attention + epilogue t = ao*alpha + z  (bf16 out).
// Grid (L/128, B*H), 512 thr = 8 waves x 16 q-rows = 128 q per block.
// Swapped QK^T: S^T[key][q] = K·Q^T so softmax reduce = regs + shfl_xor(16,32).
// ---------------------------------------------------------------------------
__global__ __launch_bounds__(512) void attn_mfma(
    const ushort* __restrict__ znb, const ushort* __restrict__ kvb,
    const float* __restrict__ zres, const float* __restrict__ alpha_p,
    ushort* __restrict__ tb)
{
    const int b = blockIdx.y >> 2, h = blockIdx.y & 3;
    const int q0 = blockIdx.x * 128;
    const int tid = threadIdx.x;
    const int l = tid & 63, w = tid >> 6;
    const int lg = l >> 4, lr = l & 15;

    __shared__ ushort Ks[64 * 64];      // [key][dim], 16B-slot swizzled
    __shared__ ushort Vt[64 * 72];      // [dim][key], padded stride 72
    __shared__ ushort Pt[8][16 * 64];   // per-wave P[q][key], swizzled

    const long qrow = (long)b * L_SEQ + q0 + w * 16 + lr;
    const sv8 qf0 = *(const sv8*)&znb[qrow * PDIM + h * 64 + lg * 8];
    const sv8 qf1 = *(const sv8*)&znb[qrow * PDIM + h * 64 + 32 + lg * 8];

    float m_col = -3.0e38f, l_col = 0.0f;
    fv4 o_acc[4];
    #pragma unroll
    for (int nt = 0; nt < 4; nt++) o_acc[nt] = (fv4){0.f, 0.f, 0.f, 0.f};

    const ushort* kvh = kvb + (long)b * L_SEQ * 512 + h * 64;

    for (int kt = 0; kt < L_SEQ / 64; kt++) {
        __syncthreads();
        {   // stage K (512 threads -> one sv8 slot each)
            int r = tid >> 3, sl = tid & 7;
            sv8 v = *(const sv8*)&kvh[(long)(kt * 64 + r) * 512 + sl * 8];
            *(sv8*)&Ks[r * 64 + ((sl ^ (r & 7)) * 8)] = v;
        }
        {   // stage V transposed (rotated scatter)
            int key = tid >> 3, dblk = tid & 7;
            sv8 v = *(const sv8*)&kvh[(long)(kt * 64 + key) * 512 + 256 + dblk * 8];
            #pragma unroll
            for (int j = 0; j < 8; j++) {
                int jj = (j + dblk) & 7;         // vary dim&7 across lanes per inst
                Vt[(dblk * 8 + jj) * 72 + key] = ((const ushort*)&v)[jj];
            }
        }
        __syncthreads();

        // S^T = K · Q^T   (4 key-tiles x K=64)
        fv4 st[4];
        __builtin_amdgcn_s_setprio(1);
        #pragma unroll
        for (int mt = 0; mt < 4; mt++) {
            st[mt] = (fv4){0.f, 0.f, 0.f, 0.f};
            int r = mt * 16 + lr;
            sv8 ka0 = *(const sv8*)&Ks[r * 64 + ((lg ^ (r & 7)) * 8)];
            sv8 ka1 = *(const sv8*)&Ks[r * 64 + (((4 + lg) ^ (r & 7)) * 8)];
            st[mt] = __builtin_amdgcn_mfma_f32_16x16x32_bf16(ka0, qf0, st[mt], 0, 0, 0);
            st[mt] = __builtin_amdgcn_mfma_f32_16x16x32_bf16(ka1, qf1, st[mt], 0, 0, 0);
        }
        __builtin_amdgcn_s_setprio(0);
        // online softmax (per q-col = lr)
        float mx = m_col;
        #pragma unroll
        for (int mt = 0; mt < 4; mt++)
            #pragma unroll
            for (int e = 0; e < 4; e++)
                mx = fmaxf(mx, st[mt][e] * 0.125f);
        mx = fmaxf(mx, __shfl_xor(mx, 16));
        mx = fmaxf(mx, __shfl_xor(mx, 32));
        float ps = 0.f;
        #pragma unroll
        for (int mt = 0; mt < 4; mt++)
            #pragma unroll
            for (int e = 0; e < 4; e++) {
                float p = __expf(st[mt][e] * 0.125f - mx);
                st[mt][e] = p;
                ps += p;
            }
        float rs = __expf(m_col - mx);
        ps += __shfl_xor(ps, 16);
        ps += __shfl_xor(ps, 32);
        l_col = l_col * rs + ps;
        m_col = mx;
        // P -> per-wave LDS (bf16) in A-frag layout
        #pragma unroll
        for (int mt = 0; mt < 4; mt++) {
            sv4 pw;
            pw[0] = f2bs(st[mt][0]); pw[1] = f2bs(st[mt][1]);
            pw[2] = f2bs(st[mt][2]); pw[3] = f2bs(st[mt][3]);
            int slot = 2 * mt + (lg >> 1);
            int idx = lr * 64 + ((slot ^ (lr & 7)) * 8) + 4 * (lg & 1);
            *(sv4*)&Pt[w][idx] = pw;
        }
        // O rescale (rows are q: fetch rs for q = lg*4+e from lane q)
        float rs_row[4];
        #pragma unroll
        for (int e = 0; e < 4; e++) rs_row[e] = __shfl(rs, lg * 4 + e);
        #pragma unroll
        for (int nt = 0; nt < 4; nt++)
            #pragma unroll
            for (int e = 0; e < 4; e++)
                o_acc[nt][e] *= rs_row[e];
        // O += P @ V
        __builtin_amdgcn_s_setprio(1);
        #pragma unroll
        for (int kk = 0; kk < 2; kk++) {
            sv8 pa = *(const sv8*)&Pt[w][lr * 64 + (((kk * 4 + lg) ^ (lr & 7)) * 8)];
            #pragma unroll
            for (int nt = 0; nt < 4; nt++) {
                int dim = nt * 16 + lr;
                sv8 vb = *(const sv8*)&Vt[dim * 72 + kk * 32 + lg * 8];
                o_acc[nt] = __builtin_amdgcn_mfma_f32_16x16x32_bf16(pa, vb, o_acc[nt], 0, 0, 0);
            }
        }
        __builtin_amdgcn_s_setprio(0);
    }
    float linv = 1.0f / l_col;
    float li_row[4];
    #pragma unroll
    for (int e = 0; e < 4; e++) li_row[e] = __shfl(linv, lg * 4 + e);
    const float a = alpha_p[0];
    #pragma unroll
    for (int nt = 0; nt < 4; nt++)
        #pragma unroll
        for (int e = 0; e < 4; e++) {
            long row = (long)b * L_SEQ + q0 + w * 16 + lg * 4 + e;
            int col = h * 64 + nt * 16 + lr;
            float t = o_acc[nt][e] * li_row[e] * a + zres[row * PDIM + col];
            tb[row * PDIM + col] = f2bs(t);
        }
}

// ---------------------------------------------------------------------------
// f32 -> bf16 cast (x -> hb), 4 elems/thread.
// ---------------------------------------------------------------------------
__global__ __launch_bounds__(256) void cast_bf16(
    const float* __restrict__ in, ushort* __restrict__ out)
{
    long i = (long)blockIdx.x * 256 + threadIdx.x;
    float4 v = ((const float4*)in)[i];
    sv4 o;
    o[0] = f2bs(v.x); o[1] = f2bs(v.y); o[2] = f2bs(v.z); o[3] = f2bs(v.w);
    *(sv4*)&out[i * 4] = o;
}

// ---------------------------------------------------------------------------
// Weight transpose + cast: W[K][N] f32 -> Wt[N][K] bf16 (32x32 tiles).
// ---------------------------------------------------------------------------
__global__ __launch_bounds__(256) void tcast(
    const float* __restrict__ W, ushort* __restrict__ Wt, int K, int N)
{
    __shared__ float t[32][33];
    const int n0 = blockIdx.x * 32, k0 = blockIdx.y * 32;
    const int c = threadIdx.x & 31, r = threadIdx.x >> 5;
    #pragma unroll
    for (int i = 0; i < 4; i++)
        t[r + i * 8][c] = W[(long)(k0 + r + i * 8) * N + n0 + c];
    __syncthreads();
    #pragma unroll
    for (int i = 0; i < 4; i++)
        Wt[(long)(n0 + r + i * 8) * K + k0 + c] = f2bs(t[c][r + i * 8]);
}

// ---------------------------------------------------------------------------
// SRU recurrence, one SCHUNK of 512 steps. Transposed U (Ut[ch][b*512+t]).
// x read as bf16 from hb (in-place). WMODE 0 (layer 0): write h -> hb only
// (bf16). WMODE 1 (last layer): write h -> hout only (f32).
// 32-step double-buffered register prefetch (A/B, static indexing): batch
// t0+32's loads issue before computing t0's 32 steps (~1300 cyc cover).
// Short c-chain: FMA -> MUL -> V_EXP -> ADD -> V_RCP -> FMA  (~35 cyc/step).
// cstate = c_finals region of d_out; chunk 0 seeds from c0 (deterministic).
// ---------------------------------------------------------------------------
#define SCAN_LOAD(S, T0)                                               \
    {                                                                  \
        _Pragma("unroll")                                              \
        for (int q = 0; q < 4; q++) {                                  \
            u0##S[q] = *(const sv8*)&u0p[(T0) + q * 8];                \
            u1##S[q] = *(const sv8*)&u1p[(T0) + q * 8];                \
            u2##S[q] = *(const sv8*)&u2p[(T0) + q * 8];                \
        }                                                              \
        _Pragma("unroll")                                              \
        for (int j = 0; j < 32; j++)                                   \
            x##S[j] = xbp[(long)((T0) + j) * DMODEL];                  \
    }

#define SCAN_COMPUTE(S, T0)                                            \
    {                                                                  \
        _Pragma("unroll")                                              \
        for (int j = 0; j < 32; j++) {                                 \
            float u0 = bs2f((ushort)u0##S[j >> 3][j & 7]);             \
            float a1 = bs2f((ushort)u1##S[j >> 3][j & 7]) + bfc;       \
            float a2 = bs2f((ushort)u2##S[j >> 3][j & 7]) + brc;       \
            float xv = bs2f(x##S[j]);                                  \
            float e1 = __expf(-(a1 + vf * c));                         \
            float f  = __builtin_amdgcn_rcpf(1.0f + e1);               \
            c = u0 + (c - u0) * f;                                     \
            float e2 = __expf(-(a2 + vr * c));                         \
            float r  = __builtin_amdgcn_rcpf(1.0f + e2);               \
            float hv = (c - xv) * r + xv;                              \
            if (WMODE == 0) xbp[(long)((T0) + j) * DMODEL] = f2bs(hv); \
            else            hp[(long)((T0) + j) * DMODEL]  = hv;       \
        }                                                              \
    }

template<int WMODE>
__global__ __launch_bounds__(64) void scan_chunk_t(
    const ushort* __restrict__ Ut, ushort* __restrict__ hb,
    float* __restrict__ hout,
    float* __restrict__ cstate, const float* __restrict__ c0,
    const float* __restrict__ wcl, const float* __restrict__ biasl, int chunk)
{
    const int gid = blockIdx.x * 64 + threadIdx.x;   // 0..4095
    const int b = gid >> 10, ch = gid & 1023;
    const float vf = wcl[ch],    vr = wcl[DMODEL + ch];
    const float bfc = biasl[ch], brc = biasl[DMODEL + ch];
    float c = (chunk == 0) ? c0[gid] : cstate[gid];
    const ushort* u0p = Ut + (long)ch * (BATCH * SCHUNK) + b * SCHUNK;
    const ushort* u1p = u0p + (long)1024 * (BATCH * SCHUNK);
    const ushort* u2p = u0p + (long)2048 * (BATCH * SCHUNK);
    const long xoff = (long)b * L_SEQ * DMODEL + (long)chunk * SCHUNK * DMODEL + ch;
    ushort* xbp = hb + xoff;     // bf16 x in; h out when WMODE==0 (in-place)
    float*  hp  = hout + xoff;   // f32 h out when WMODE==1

    sv8 u0A[4], u1A[4], u2A[4], u0B[4], u1B[4], u2B[4];
    ushort xA[32], xB[32];
    SCAN_LOAD(A, 0)
    SCAN_LOAD(B, 32)
    for (int t0 = 0; t0 < SCHUNK; t0 += 64) {
        SCAN_COMPUTE(A, t0)
        if (t0 + 64 < SCHUNK) SCAN_LOAD(A, t0 + 64)
        SCAN_COMPUTE(B, t0 + 32)
        if (t0 + 96 < SCHUNK) SCAN_LOAD(B, t0 + 96)
    }
    cstate[gid] = c;
}

// ---------------------------------------------------------------------------
extern "C" void kernel_launch(void* const* d_in, const int* in_sizes, int n_in,
                              void* d_out, int out_size, void* d_ws, size_t ws_size,
                              hipStream_t stream)
{
    const float* x     = (const float*)d_in[0];
    const float* W1    = (const float*)d_in[1];
    const float* ln_g  = (const float*)d_in[2];
    const float* ln_b  = (const float*)d_in[3];
    const float* W2    = (const float*)d_in[4];
    const float* alpha = (const float*)d_in[5];
    const float* W3    = (const float*)d_in[6];
    const float* wc    = (const float*)d_in[7];
    const float* bias  = (const float*)d_in[8];
    const float* c0    = (const float*)d_in[9];

    float* hout = (float*)d_out;                              // (B,L,D)
    float* cout = hout + (long)BATCH * L_SEQ * DMODEL;        // (nl,B,D)

    // ws layout (44.3 MB; bf16 Ut overlays dead znb+kvb exactly: 12.58 MB)
    ushort* hb   = (ushort*)d_ws;                             // 16.8 MB  bf16 h
    float*  z    = (float*)(hb + (long)8192 * 1024);          // 8.4 MB
    ushort* znb  = (ushort*)(z + (long)8192 * 256);           // 4.2 MB
    ushort* kvb  = znb + (long)8192 * 256;                    // 8.4 MB
    ushort* tbuf = kvb + (long)8192 * 512;                    // 4.2 MB
    ushort* W1t  = tbuf + (long)8192 * 256;                   // 0.5 MB
    ushort* W2t  = W1t + 256 * 1024;                          // 0.25 MB
    ushort* W3t  = W2t + 512 * 256;                           // 1.5 MB
    ushort* Ut   = znb;   // bf16 [3072][B*512] = 12.58 MB, fits znb+kvb

    // x -> bf16 (8192*1024 elems, 4/thread)
    cast_bf16<<<8192, 256, 0, stream>>>(x, hb);

    for (int l = 0; l < NLAYERS; l++) {
        // weights -> transposed bf16 [N][K]
        tcast<<<dim3(PDIM / 32, DMODEL / 32), 256, 0, stream>>>(
            W1 + (long)l * DMODEL * PDIM, W1t, DMODEL, PDIM);
        tcast<<<dim3(2 * PDIM / 32, PDIM / 32), 256, 0, stream>>>(
            W2 + (long)l * PDIM * 2 * PDIM, W2t, PDIM, 2 * PDIM);
        tcast<<<dim3(3 * DMODEL / 32, PDIM / 32), 256, 0, stream>>>(
            W3 + (long)l * PDIM * 3 * DMODEL, W3t, PDIM, 3 * DMODEL);

        // z = h @ W1   (8192 x 1024 -> 256), f32 out
        gemm_mfma<64, false><<<dim3(PDIM / 64, 8192 / 128, 1), 256, 0, stream>>>(
            hb, W1t, z, DMODEL, PDIM, 0, 0, 0);

        // zn = LN(z) -> bf16
        ln_kernel<<<8192, 256, 0, stream>>>(z, ln_g + l * PDIM, ln_b + l * PDIM, znb);

        // kv = zn @ W2  (8192 x 256 -> 512), bf16 out
        gemm_mfma<128, true><<<dim3(512 / 128, 8192 / 128, 1), 256, 0, stream>>>(
            znb, W2t, kvb, PDIM, 512, 0, 0, 0);

        // t = attn(zn)*alpha + z -> bf16   (128 q-rows per 512-thread block)
        attn_mfma<<<dim3(L_SEQ / 128, BATCH * NHEADS), 512, 0, stream>>>(
            znb, kvb, z, alpha + l, tbuf);

        // U^T = W3t @ t^T per 512-chunk:  Ut[m][b*512+t], m in [0,3072)
        for (int cch = 0; cch < NCHUNK; cch++) {
            gemm_mfma<128, true><<<dim3(SCHUNK / 128, 3072 / 128, BATCH), 256, 0, stream>>>(
                W3t, tbuf + (long)cch * SCHUNK * PDIM, Ut, PDIM, BATCH * SCHUNK,
                0, (long)L_SEQ * PDIM, SCHUNK);
            if (l == 0)
                scan_chunk_t<0><<<64, 64, 0, stream>>>(
                    Ut, hb, hout,
                    cout + (long)l * BATCH * DMODEL, c0 + (long)l * BATCH * DMODEL,
                    wc + (long)l * 2 * DMODEL, bias + (long)l * 2 * DMODEL, cch);
            else
                scan_chunk_t<1><<<64, 64, 0, stream>>>(
                    Ut, hb, hout,
                    cout + (long)l * BATCH * DMODEL, c0 + (long)l * BATCH * DMODEL,
                    wc + (long)l * 2 * DMODEL, bias + (long)l * 2 * DMODEL, cch);
        }
    }
}